// Round 5
// baseline (834.177 us; speedup 1.0000x reference)
//
#include <hip/hip_runtime.h>
#include <math.h>

typedef unsigned short bfu;

__device__ __forceinline__ float b2f(bfu u) {
    unsigned int x = ((unsigned int)u) << 16;
    return __uint_as_float(x);
}
__device__ __forceinline__ bfu f2bf(float f) {
    unsigned int u = __float_as_uint(f);
    unsigned int r = (u + 0x7FFFu + ((u >> 16) & 1u)) >> 16;
    return (bfu)r;
}

// ---------------------------------------------------------------------------
// fused zero: deg[N], cdeg[NC], sumsq[512]
// ---------------------------------------------------------------------------
__global__ void k_zero3(int* __restrict__ deg, int N, int* __restrict__ cdeg, int NC,
                        float* __restrict__ sumsq) {
    int i = blockIdx.x * blockDim.x + threadIdx.x;
    if (i < N) deg[i] = 0;
    if (i < NC) cdeg[i] = 0;
    if (i < 512) sumsq[i] = 0.f;
}

// ---------------------------------------------------------------------------
// CSR build: histogram -> hierarchical scan -> scatter
// ---------------------------------------------------------------------------
__global__ void k_hist(const int* __restrict__ keys, int n, int* __restrict__ deg) {
    int i = blockIdx.x * blockDim.x + threadIdx.x;
    if (i < n) atomicAdd(&deg[keys[i]], 1);
}

// Phase A: per-block (256-wide) inclusive scan; store inclusive + block sum.
__global__ __launch_bounds__(256) void k_scanA(const int* __restrict__ deg, int N,
                                               const int* __restrict__ cdeg, int NC,
                                               int* __restrict__ scn0, int* __restrict__ scn1,
                                               int* __restrict__ bsum0, int* __restrict__ bsum1) {
    __shared__ int part[256];
    const int seg = blockIdx.y;
    const int n = seg ? NC : N;
    const int* d = seg ? cdeg : deg;
    int* scn = seg ? scn1 : scn0;
    int* bs  = seg ? bsum1 : bsum0;
    const int b = blockIdx.x;
    if (b * 256 >= n) return;
    const int t = threadIdx.x;
    const int i = b * 256 + t;
    int v = (i < n) ? d[i] : 0;
    part[t] = v;
    __syncthreads();
#pragma unroll
    for (int off = 1; off < 256; off <<= 1) {
        int cv = part[t];
        int u = (t >= off) ? part[t - off] : 0;
        __syncthreads();
        part[t] = cv + u;
        __syncthreads();
    }
    if (i < n) scn[i] = part[t];
    if (t == 255) bs[b] = part[255];
}

// Phase B: single block, exclusive-scan the block sums for both segments.
__global__ __launch_bounds__(256) void k_scanB(int* __restrict__ bsum0, int nb0,
                                               int* __restrict__ bsum1, int nb1,
                                               int* __restrict__ ptr0, int N,
                                               int* __restrict__ ptr1, int NC) {
    __shared__ int part[256];
    const int t = threadIdx.x;
    int v = (t < nb0) ? bsum0[t] : 0;
    part[t] = v;
    __syncthreads();
#pragma unroll
    for (int off = 1; off < 256; off <<= 1) {
        int cv = part[t];
        int u = (t >= off) ? part[t - off] : 0;
        __syncthreads();
        part[t] = cv + u;
        __syncthreads();
    }
    if (t < nb0) bsum0[t] = part[t] - v;
    if (t == 255) ptr0[N] = part[255];
    __syncthreads();
    v = (t < nb1) ? bsum1[t] : 0;
    part[t] = v;
    __syncthreads();
#pragma unroll
    for (int off = 1; off < 256; off <<= 1) {
        int cv = part[t];
        int u = (t >= off) ? part[t - off] : 0;
        __syncthreads();
        part[t] = cv + u;
        __syncthreads();
    }
    if (t < nb1) bsum1[t] = part[t] - v;
    if (t == 255) ptr1[NC] = part[255];
}

// Phase C: ptr[i] = blockoff + incl[i] - d[i]  (exclusive), dup into cursor.
__global__ __launch_bounds__(256) void k_scanC(const int* __restrict__ deg, int N,
                                               const int* __restrict__ cdeg, int NC,
                                               const int* __restrict__ scn0, const int* __restrict__ scn1,
                                               const int* __restrict__ bsum0, const int* __restrict__ bsum1,
                                               int* __restrict__ ptr0, int* __restrict__ cur0,
                                               int* __restrict__ ptr1, int* __restrict__ cur1) {
    const int seg = blockIdx.y;
    const int n = seg ? NC : N;
    const int* d = seg ? cdeg : deg;
    const int* scn = seg ? scn1 : scn0;
    const int* bs  = seg ? bsum1 : bsum0;
    int* ptr = seg ? ptr1 : ptr0;
    int* cur = seg ? cur1 : cur0;
    const int b = blockIdx.x;
    if (b * 256 >= n) return;
    const int i = b * 256 + threadIdx.x;
    if (i < n) {
        int e = bs[b] + scn[i] - d[i];
        ptr[i] = e;
        cur[i] = e;
    }
}

__global__ void k_scatter_edges(const int* __restrict__ dst, const int* __restrict__ src,
                                int E, int* __restrict__ cur, int* __restrict__ colidx) {
    int e = blockIdx.x * blockDim.x + threadIdx.x;
    if (e < E) {
        int d = dst[e];
        int pos = atomicAdd(&cur[d], 1);
        colidx[pos] = src[e];
    }
}

__global__ void k_scatter_nodes(const int* __restrict__ key, int N,
                                int* __restrict__ cur, int* __restrict__ idx) {
    int i = blockIdx.x * blockDim.x + threadIdx.x;
    if (i < N) {
        int c = key[i];
        int pos = atomicAdd(&cur[c], 1);
        idx[pos] = i;
    }
}

// ---------------------------------------------------------------------------
// Unified GEMM: out = act(x @ w + bias)
//   x:[M,K] stride K, w:[K,Nw] stride Nw, 128x64 tile, 256 thr, 8x4 frag.
//   Thread rows: rl+16*i (conflict-free A reads); f32 out at row stride OS with
//   col offset n0; DUAL also writes bf16 copy at row stride Nw.
// ---------------------------------------------------------------------------
template <int K, bool RELU, bool DUAL>
__global__ __launch_bounds__(256) void k_gemm(const float* __restrict__ x,
                                              const float* __restrict__ w,
                                              const float* __restrict__ bias,
                                              float* __restrict__ outf,
                                              bfu* __restrict__ outb,
                                              int M, int Nw, int OS) {
    __shared__ float xs[128][68];
    __shared__ float ws[64][68];
    const int tid = threadIdx.x;
    const int rl = tid >> 4;          // 0..15
    const int c4 = (tid & 15) * 4;    // 0..60
    const int m0 = blockIdx.x * 128;
    const int n0 = blockIdx.y * 64;

    float acc[8][4] = {};

    for (int k0 = 0; k0 < K; k0 += 64) {
        __syncthreads();
#pragma unroll
        for (int i = 0; i < 8; i++) {
            int r = rl + 16 * i;
            int gm = m0 + r;
            int gmc = gm < M ? gm : M - 1;
            float4 v = *(const float4*)&x[(size_t)gmc * K + k0 + c4];
            *(float4*)&xs[r][c4] = v;
        }
#pragma unroll
        for (int i = 0; i < 4; i++) {
            int kr = rl + 16 * i;
            float4 v = *(const float4*)&w[(size_t)(k0 + kr) * Nw + n0 + c4];
            *(float4*)&ws[kr][c4] = v;
        }
        __syncthreads();
#pragma unroll
        for (int kk = 0; kk < 64; kk += 4) {
            float4 b0 = *(const float4*)&ws[kk + 0][c4];
            float4 b1 = *(const float4*)&ws[kk + 1][c4];
            float4 b2 = *(const float4*)&ws[kk + 2][c4];
            float4 b3 = *(const float4*)&ws[kk + 3][c4];
#pragma unroll
            for (int i = 0; i < 8; i++) {
                float4 a = *(const float4*)&xs[rl + 16 * i][kk];
                acc[i][0] = fmaf(a.x, b0.x, acc[i][0]);
                acc[i][1] = fmaf(a.x, b0.y, acc[i][1]);
                acc[i][2] = fmaf(a.x, b0.z, acc[i][2]);
                acc[i][3] = fmaf(a.x, b0.w, acc[i][3]);
                acc[i][0] = fmaf(a.y, b1.x, acc[i][0]);
                acc[i][1] = fmaf(a.y, b1.y, acc[i][1]);
                acc[i][2] = fmaf(a.y, b1.z, acc[i][2]);
                acc[i][3] = fmaf(a.y, b1.w, acc[i][3]);
                acc[i][0] = fmaf(a.z, b2.x, acc[i][0]);
                acc[i][1] = fmaf(a.z, b2.y, acc[i][1]);
                acc[i][2] = fmaf(a.z, b2.z, acc[i][2]);
                acc[i][3] = fmaf(a.z, b2.w, acc[i][3]);
                acc[i][0] = fmaf(a.w, b3.x, acc[i][0]);
                acc[i][1] = fmaf(a.w, b3.y, acc[i][1]);
                acc[i][2] = fmaf(a.w, b3.z, acc[i][2]);
                acc[i][3] = fmaf(a.w, b3.w, acc[i][3]);
            }
        }
    }

    float4 bb = *(const float4*)&bias[n0 + c4];
#pragma unroll
    for (int i = 0; i < 8; i++) {
        int gm = m0 + rl + 16 * i;
        if (gm < M) {
            float4 o;
            o.x = acc[i][0] + bb.x;
            o.y = acc[i][1] + bb.y;
            o.z = acc[i][2] + bb.z;
            o.w = acc[i][3] + bb.w;
            if (RELU) {
                o.x = fmaxf(o.x, 0.f); o.y = fmaxf(o.y, 0.f);
                o.z = fmaxf(o.z, 0.f); o.w = fmaxf(o.w, 0.f);
            }
            *(float4*)&outf[(size_t)gm * OS + n0 + c4] = o;
            if (DUAL) {
                ushort4 hq;
                hq.x = f2bf(o.x); hq.y = f2bf(o.y);
                hq.z = f2bf(o.z); hq.w = f2bf(o.w);
                *(ushort4*)&outb[(size_t)gm * Nw + n0 + c4] = hq;
            }
        }
    }
}

// ---------------------------------------------------------------------------
// Aggregation: per-node max over incoming edges (CSR), wave per node.
// Gather table hb is dense bf16 [N, 64*R]; output f32 at `ostride`.
// ---------------------------------------------------------------------------
template <int R>
__global__ void k_agg(const bfu* __restrict__ hb, float* __restrict__ aggr,
                      const int* __restrict__ rowptr, const int* __restrict__ colidx,
                      int N, int ostride) {
    const int wid = (blockIdx.x * blockDim.x + threadIdx.x) >> 6;
    const int lane = threadIdx.x & 63;
    if (wid >= N) return;
    const int beg = rowptr[wid], end = rowptr[wid + 1];
    const int cb = 64 * R;
    const int ch = lane * R;

    float acc[R];
#pragma unroll
    for (int r = 0; r < R; r++) acc[r] = -INFINITY;

    int i = beg;
    for (; i + 4 <= end; i += 4) {
        int s0 = colidx[i + 0], s1 = colidx[i + 1];
        int s2 = colidx[i + 2], s3 = colidx[i + 3];
        const bfu* p0 = hb + (size_t)s0 * cb + ch;
        const bfu* p1 = hb + (size_t)s1 * cb + ch;
        const bfu* p2 = hb + (size_t)s2 * cb + ch;
        const bfu* p3 = hb + (size_t)s3 * cb + ch;
        if (R == 4) {
            ushort4 v0 = *(const ushort4*)p0;
            ushort4 v1 = *(const ushort4*)p1;
            ushort4 v2 = *(const ushort4*)p2;
            ushort4 v3 = *(const ushort4*)p3;
            acc[0] = fmaxf(acc[0], fmaxf(fmaxf(b2f(v0.x), b2f(v1.x)), fmaxf(b2f(v2.x), b2f(v3.x))));
            acc[1] = fmaxf(acc[1], fmaxf(fmaxf(b2f(v0.y), b2f(v1.y)), fmaxf(b2f(v2.y), b2f(v3.y))));
            acc[2] = fmaxf(acc[2], fmaxf(fmaxf(b2f(v0.z), b2f(v1.z)), fmaxf(b2f(v2.z), b2f(v3.z))));
            acc[3] = fmaxf(acc[3], fmaxf(fmaxf(b2f(v0.w), b2f(v1.w)), fmaxf(b2f(v2.w), b2f(v3.w))));
        } else if (R == 2) {
            ushort2 v0 = *(const ushort2*)p0;
            ushort2 v1 = *(const ushort2*)p1;
            ushort2 v2 = *(const ushort2*)p2;
            ushort2 v3 = *(const ushort2*)p3;
            acc[0] = fmaxf(acc[0], fmaxf(fmaxf(b2f(v0.x), b2f(v1.x)), fmaxf(b2f(v2.x), b2f(v3.x))));
            acc[1] = fmaxf(acc[1], fmaxf(fmaxf(b2f(v0.y), b2f(v1.y)), fmaxf(b2f(v2.y), b2f(v3.y))));
        } else {
            bfu v0 = *p0, v1 = *p1, v2 = *p2, v3 = *p3;
            acc[0] = fmaxf(acc[0], fmaxf(fmaxf(b2f(v0), b2f(v1)), fmaxf(b2f(v2), b2f(v3))));
        }
    }
    for (; i < end; i++) {
        int s = colidx[i];
        const bfu* p = hb + (size_t)s * cb + ch;
        if (R == 4) {
            ushort4 v = *(const ushort4*)p;
            acc[0] = fmaxf(acc[0], b2f(v.x)); acc[1] = fmaxf(acc[1], b2f(v.y));
            acc[2] = fmaxf(acc[2], b2f(v.z)); acc[3] = fmaxf(acc[3], b2f(v.w));
        } else if (R == 2) {
            ushort2 v = *(const ushort2*)p;
            acc[0] = fmaxf(acc[0], b2f(v.x)); acc[1] = fmaxf(acc[1], b2f(v.y));
        } else {
            acc[0] = fmaxf(acc[0], b2f(*p));
        }
    }

    if (beg == end) {
#pragma unroll
        for (int r = 0; r < R; r++) acc[r] = 0.f;
    }
    float* q = aggr + (size_t)wid * ostride + ch;
#pragma unroll
    for (int r = 0; r < R; r++) q[r] = acc[r];
}

// ---------------------------------------------------------------------------
// Cluster max-pool: block per cluster, 256 thr x float2; 4-deep unrolled gather
// ---------------------------------------------------------------------------
__global__ void k_pool(const float* __restrict__ x3, const int* __restrict__ cptr,
                       const int* __restrict__ cidx, float* __restrict__ pooled) {
    int cl = blockIdx.x;
    int tid = threadIdx.x;
    int beg = cptr[cl], end = cptr[cl + 1];
    float ax = -INFINITY, ay = -INFINITY;
    int i = beg;
    for (; i + 4 <= end; i += 4) {
        int n0 = cidx[i + 0], n1 = cidx[i + 1];
        int n2 = cidx[i + 2], n3 = cidx[i + 3];
        float2 v0 = *(const float2*)&x3[(size_t)n0 * 512 + tid * 2];
        float2 v1 = *(const float2*)&x3[(size_t)n1 * 512 + tid * 2];
        float2 v2 = *(const float2*)&x3[(size_t)n2 * 512 + tid * 2];
        float2 v3 = *(const float2*)&x3[(size_t)n3 * 512 + tid * 2];
        ax = fmaxf(ax, fmaxf(fmaxf(v0.x, v1.x), fmaxf(v2.x, v3.x)));
        ay = fmaxf(ay, fmaxf(fmaxf(v0.y, v1.y), fmaxf(v2.y, v3.y)));
    }
    for (; i < end; i++) {
        int n = cidx[i];
        float2 v = *(const float2*)&x3[(size_t)n * 512 + tid * 2];
        ax = fmaxf(ax, v.x); ay = fmaxf(ay, v.y);
    }
    if (beg == end) { ax = 0.f; ay = 0.f; }
    float2 o; o.x = ax; o.y = ay;
    *(float2*)&pooled[(size_t)cl * 512 + tid * 2] = o;
}

// ---------------------------------------------------------------------------
// Column-wise sum of squares (axis 0), low-contention (64 blocks)
// ---------------------------------------------------------------------------
__global__ void k_sumsq(const float* __restrict__ pooled, float* __restrict__ sumsq, int NC) {
    int tid = threadIdx.x;
    float ax = 0.f, ay = 0.f;
    for (int r = blockIdx.x; r < NC; r += gridDim.x) {
        float2 v = *(const float2*)&pooled[(size_t)r * 512 + tid * 2];
        ax += v.x * v.x; ay += v.y * v.y;
    }
    atomicAdd(&sumsq[tid * 2 + 0], ax);
    atomicAdd(&sumsq[tid * 2 + 1], ay);
}

__global__ void k_scale(const float* __restrict__ pooled, const float* __restrict__ sumsq,
                        float* __restrict__ out, int total) {
    int i = blockIdx.x * blockDim.x + threadIdx.x;
    int base = i * 4;
    if (base < total) {
        float4 v = *(const float4*)&pooled[base];
        int col = base & 511;
        v.x /= (sqrtf(sumsq[col + 0]) + 1e-6f);
        v.y /= (sqrtf(sumsq[col + 1]) + 1e-6f);
        v.z /= (sqrtf(sumsq[col + 2]) + 1e-6f);
        v.w /= (sqrtf(sumsq[col + 3]) + 1e-6f);
        *(float4*)&out[base] = v;
    }
}

// ---------------------------------------------------------------------------
extern "C" void kernel_launch(void* const* d_in, const int* in_sizes, int n_in,
                              void* d_out, int out_size, void* d_ws, size_t ws_size,
                              hipStream_t stream) {
    const float* x0      = (const float*)d_in[0];
    const int*   ei      = (const int*)d_in[1];
    const int*   cluster = (const int*)d_in[2];
    const float* w1_[3] = {(const float*)d_in[3], (const float*)d_in[7],  (const float*)d_in[11]};
    const float* b1_[3] = {(const float*)d_in[4], (const float*)d_in[8],  (const float*)d_in[12]};
    const float* w2_[3] = {(const float*)d_in[5], (const float*)d_in[9],  (const float*)d_in[13]};
    const float* b2_[3] = {(const float*)d_in[6], (const float*)d_in[10], (const float*)d_in[14]};

    const int N  = in_sizes[2];       // 50000
    const int E  = in_sizes[1] / 2;   // 800000
    const int NC = 2500;
    float* out = (float*)d_out;

    char* p = (char*)d_ws;
    auto alloc = [&](size_t bytes) -> char* {
        char* r = p;
        p += (bytes + 255) & ~(size_t)255;
        return r;
    };
    float* x1     = (float*)alloc((size_t)N * 128 * 4);
    float* x2     = (float*)alloc((size_t)N * 256 * 4);
    float* x3     = (float*)alloc((size_t)N * 512 * 4);
    float* tbuf   = (float*)alloc((size_t)N * 64 * 4);
    bfu*   hb0    = (bfu*)alloc((size_t)N * 64 * 2);
    bfu*   hb1    = (bfu*)alloc((size_t)N * 128 * 2);
    bfu*   hb2    = (bfu*)alloc((size_t)N * 256 * 2);
    float* pooled = (float*)alloc((size_t)NC * 512 * 4);
    float* sumsq  = (float*)alloc(512 * 4);
    int*   deg    = (int*)alloc((size_t)(N + 1) * 4);
    int*   rowptr = (int*)alloc((size_t)(N + 1) * 4);
    int*   cursor = (int*)alloc((size_t)(N + 1) * 4);
    int*   colidx = (int*)alloc((size_t)E * 4);
    int*   cdeg   = (int*)alloc((size_t)(NC + 1) * 4);
    int*   cptr   = (int*)alloc((size_t)(NC + 1) * 4);
    int*   ccur   = (int*)alloc((size_t)(NC + 1) * 4);
    int*   cidx   = (int*)alloc((size_t)N * 4);
    int*   scn0   = (int*)alloc((size_t)N * 4);
    int*   scn1   = (int*)alloc((size_t)NC * 4);
    int*   bsum0  = (int*)alloc(256 * 4);
    int*   bsum1  = (int*)alloc(256 * 4);

    const int* src = ei;
    const int* dst = ei + E;

    k_zero3<<<(N + 255) / 256, 256, 0, stream>>>(deg, N, cdeg, NC, sumsq);

    // histograms
    k_hist<<<(E + 255) / 256, 256, 0, stream>>>(dst, E, deg);
    k_hist<<<(N + 255) / 256, 256, 0, stream>>>(cluster, N, cdeg);

    // hierarchical exclusive scan of both segments
    const int nb0 = (N + 255) / 256;
    const int nb1 = (NC + 255) / 256;
    k_scanA<<<dim3(nb0, 2), 256, 0, stream>>>(deg, N, cdeg, NC, scn0, scn1, bsum0, bsum1);
    k_scanB<<<1, 256, 0, stream>>>(bsum0, nb0, bsum1, nb1, rowptr, N, cptr, NC);
    k_scanC<<<dim3(nb0, 2), 256, 0, stream>>>(deg, N, cdeg, NC, scn0, scn1, bsum0, bsum1,
                                              rowptr, cursor, cptr, ccur);

    // scatters
    k_scatter_edges<<<(E + 255) / 256, 256, 0, stream>>>(dst, src, E, cursor, colidx);
    k_scatter_nodes<<<(N + 255) / 256, 256, 0, stream>>>(cluster, N, ccur, cidx);

    const int Mt = (N + 127) / 128;
    const int aggBlocks = (N * 64 + 255) / 256;

    // layer 0: c=64
    k_gemm<64, true, false><<<dim3(Mt, 1), 256, 0, stream>>>(x0, w1_[0], b1_[0], tbuf, nullptr, N, 64, 64);
    k_gemm<64, false, true><<<dim3(Mt, 1), 256, 0, stream>>>(tbuf, w2_[0], b2_[0], x1, hb0, N, 64, 128);
    k_agg<1><<<aggBlocks, 256, 0, stream>>>(hb0, x1 + 64, rowptr, colidx, N, 128);

    // layer 1: c=128
    k_gemm<128, true, false><<<dim3(Mt, 1), 256, 0, stream>>>(x1, w1_[1], b1_[1], tbuf, nullptr, N, 64, 64);
    k_gemm<64, false, true><<<dim3(Mt, 2), 256, 0, stream>>>(tbuf, w2_[1], b2_[1], x2, hb1, N, 128, 256);
    k_agg<2><<<aggBlocks, 256, 0, stream>>>(hb1, x2 + 128, rowptr, colidx, N, 256);

    // layer 2: c=256
    k_gemm<256, true, false><<<dim3(Mt, 1), 256, 0, stream>>>(x2, w1_[2], b1_[2], tbuf, nullptr, N, 64, 64);
    k_gemm<64, false, true><<<dim3(Mt, 4), 256, 0, stream>>>(tbuf, w2_[2], b2_[2], x3, hb2, N, 256, 512);
    k_agg<4><<<aggBlocks, 256, 0, stream>>>(hb2, x3 + 256, rowptr, colidx, N, 512);

    // cluster max-pool + column norm
    k_pool<<<NC, 256, 0, stream>>>(x3, cptr, cidx, pooled);
    k_sumsq<<<64, 256, 0, stream>>>(pooled, sumsq, NC);
    k_scale<<<(out_size / 4 + 255) / 256, 256, 0, stream>>>(pooled, sumsq, out, out_size);
}

// Round 6
// 455.168 us; speedup vs baseline: 1.8327x; 1.8327x over previous
//
#include <hip/hip_runtime.h>
#include <math.h>

typedef unsigned short bfu;

__device__ __forceinline__ float b2f(bfu u) {
    unsigned int x = ((unsigned int)u) << 16;
    return __uint_as_float(x);
}
__device__ __forceinline__ bfu f2bf(float f) {
    unsigned int u = __float_as_uint(f);
    unsigned int r = (u + 0x7FFFu + ((u >> 16) & 1u)) >> 16;
    return (bfu)r;
}

// ---------------------------------------------------------------------------
// fused zero: deg[N], cdeg[NC], sumsq[512]
// ---------------------------------------------------------------------------
__global__ void k_zero3(int* __restrict__ deg, int N, int* __restrict__ cdeg, int NC,
                        float* __restrict__ sumsq) {
    int i = blockIdx.x * blockDim.x + threadIdx.x;
    if (i < N) deg[i] = 0;
    if (i < NC) cdeg[i] = 0;
    if (i < 512) sumsq[i] = 0.f;
}

// ---------------------------------------------------------------------------
// CSR build: histogram -> hierarchical scan -> scatter
// ---------------------------------------------------------------------------
__global__ void k_hist(const int* __restrict__ keys, int n, int* __restrict__ deg) {
    int i = blockIdx.x * blockDim.x + threadIdx.x;
    if (i < n) atomicAdd(&deg[keys[i]], 1);
}

// Phase A: per-block (256-wide) inclusive scan; store inclusive + block sum.
__global__ __launch_bounds__(256) void k_scanA(const int* __restrict__ deg, int N,
                                               const int* __restrict__ cdeg, int NC,
                                               int* __restrict__ scn0, int* __restrict__ scn1,
                                               int* __restrict__ bsum0, int* __restrict__ bsum1) {
    __shared__ int part[256];
    const int seg = blockIdx.y;
    const int n = seg ? NC : N;
    const int* d = seg ? cdeg : deg;
    int* scn = seg ? scn1 : scn0;
    int* bs  = seg ? bsum1 : bsum0;
    const int b = blockIdx.x;
    if (b * 256 >= n) return;
    const int t = threadIdx.x;
    const int i = b * 256 + t;
    int v = (i < n) ? d[i] : 0;
    part[t] = v;
    __syncthreads();
#pragma unroll
    for (int off = 1; off < 256; off <<= 1) {
        int cv = part[t];
        int u = (t >= off) ? part[t - off] : 0;
        __syncthreads();
        part[t] = cv + u;
        __syncthreads();
    }
    if (i < n) scn[i] = part[t];
    if (t == 255) bs[b] = part[255];
}

// Phase B: single block, exclusive-scan the block sums for both segments.
__global__ __launch_bounds__(256) void k_scanB(int* __restrict__ bsum0, int nb0,
                                               int* __restrict__ bsum1, int nb1,
                                               int* __restrict__ ptr0, int N,
                                               int* __restrict__ ptr1, int NC) {
    __shared__ int part[256];
    const int t = threadIdx.x;
    int v = (t < nb0) ? bsum0[t] : 0;
    part[t] = v;
    __syncthreads();
#pragma unroll
    for (int off = 1; off < 256; off <<= 1) {
        int cv = part[t];
        int u = (t >= off) ? part[t - off] : 0;
        __syncthreads();
        part[t] = cv + u;
        __syncthreads();
    }
    if (t < nb0) bsum0[t] = part[t] - v;
    if (t == 255) ptr0[N] = part[255];
    __syncthreads();
    v = (t < nb1) ? bsum1[t] : 0;
    part[t] = v;
    __syncthreads();
#pragma unroll
    for (int off = 1; off < 256; off <<= 1) {
        int cv = part[t];
        int u = (t >= off) ? part[t - off] : 0;
        __syncthreads();
        part[t] = cv + u;
        __syncthreads();
    }
    if (t < nb1) bsum1[t] = part[t] - v;
    if (t == 255) ptr1[NC] = part[255];
}

// Phase C: ptr[i] = blockoff + incl[i] - d[i]  (exclusive), dup into cursor.
__global__ __launch_bounds__(256) void k_scanC(const int* __restrict__ deg, int N,
                                               const int* __restrict__ cdeg, int NC,
                                               const int* __restrict__ scn0, const int* __restrict__ scn1,
                                               const int* __restrict__ bsum0, const int* __restrict__ bsum1,
                                               int* __restrict__ ptr0, int* __restrict__ cur0,
                                               int* __restrict__ ptr1, int* __restrict__ cur1) {
    const int seg = blockIdx.y;
    const int n = seg ? NC : N;
    const int* d = seg ? cdeg : deg;
    const int* scn = seg ? scn1 : scn0;
    const int* bs  = seg ? bsum1 : bsum0;
    int* ptr = seg ? ptr1 : ptr0;
    int* cur = seg ? cur1 : cur0;
    const int b = blockIdx.x;
    if (b * 256 >= n) return;
    const int i = b * 256 + threadIdx.x;
    if (i < n) {
        int e = bs[b] + scn[i] - d[i];
        ptr[i] = e;
        cur[i] = e;
    }
}

__global__ void k_scatter_edges(const int* __restrict__ dst, const int* __restrict__ src,
                                int E, int* __restrict__ cur, int* __restrict__ colidx) {
    int e = blockIdx.x * blockDim.x + threadIdx.x;
    if (e < E) {
        int d = dst[e];
        int pos = atomicAdd(&cur[d], 1);
        colidx[pos] = src[e];
    }
}

__global__ void k_scatter_nodes(const int* __restrict__ key, int N,
                                int* __restrict__ cur, int* __restrict__ idx) {
    int i = blockIdx.x * blockDim.x + threadIdx.x;
    if (i < N) {
        int c = key[i];
        int pos = atomicAdd(&cur[c], 1);
        idx[pos] = i;
    }
}

// ---------------------------------------------------------------------------
// GEMM 1: t = relu(x @ w1 + b1)   x:[M,K] (dense, stride K), w1:[K,64], t:[M,64]
// 64x64 tile, 256 threads, 4x4 register blocking (proven R4 shape, ~84 VGPR)
// ---------------------------------------------------------------------------
template <int K>
__global__ __launch_bounds__(256) void k_mlp1(const float* __restrict__ x,
                                              const float* __restrict__ w1,
                                              const float* __restrict__ b1,
                                              float* __restrict__ t, int M) {
    __shared__ float xs[64][68];
    __shared__ float ws[64][68];
    const int tid = threadIdx.x;
    const int m0 = blockIdx.x * 64;
    const int rl = tid >> 4;
    const int c4 = (tid & 15) * 4;
    float acc[4][4] = {};

    for (int k0 = 0; k0 < K; k0 += 64) {
        __syncthreads();
#pragma unroll
        for (int i = 0; i < 4; i++) {
            int r = rl + 16 * i;
            int gm = m0 + r;
            float4 v = make_float4(0.f, 0.f, 0.f, 0.f);
            if (gm < M) v = *(const float4*)&x[(size_t)gm * K + k0 + c4];
            xs[c4 + 0][r] = v.x; xs[c4 + 1][r] = v.y;
            xs[c4 + 2][r] = v.z; xs[c4 + 3][r] = v.w;
            float4 w = *(const float4*)&w1[(size_t)(k0 + r) * 64 + c4];
            *(float4*)&ws[r][c4] = w;
        }
        __syncthreads();
#pragma unroll 16
        for (int kk = 0; kk < 64; kk++) {
            float4 a = *(const float4*)&xs[kk][rl * 4];
            float4 b = *(const float4*)&ws[kk][c4];
            float ar[4] = {a.x, a.y, a.z, a.w};
            float bc[4] = {b.x, b.y, b.z, b.w};
#pragma unroll
            for (int r = 0; r < 4; r++)
#pragma unroll
                for (int c = 0; c < 4; c++)
                    acc[r][c] = fmaf(ar[r], bc[c], acc[r][c]);
        }
    }
    float4 bb = *(const float4*)&b1[c4];
    float bias[4] = {bb.x, bb.y, bb.z, bb.w};
#pragma unroll
    for (int r = 0; r < 4; r++) {
        int gm = m0 + rl * 4 + r;
        if (gm < M) {
            float4 o;
            o.x = fmaxf(acc[r][0] + bias[0], 0.f);
            o.y = fmaxf(acc[r][1] + bias[1], 0.f);
            o.z = fmaxf(acc[r][2] + bias[2], 0.f);
            o.w = fmaxf(acc[r][3] + bias[3], 0.f);
            *(float4*)&t[(size_t)gm * 64 + c4] = o;
        }
    }
}

// ---------------------------------------------------------------------------
// GEMM 2: h = t @ w2 + b2  -> f32 into out[m*OS+n], bf16 copy into hb[m*Nc+n]
// ---------------------------------------------------------------------------
__global__ __launch_bounds__(256) void k_mlp2(const float* __restrict__ t,
                                              const float* __restrict__ w2,
                                              const float* __restrict__ b2,
                                              float* __restrict__ out,
                                              bfu* __restrict__ hb,
                                              int M, int Nc, int OS) {
    __shared__ float ts[64][68];
    __shared__ float ws[64][68];
    const int tid = threadIdx.x;
    const int m0 = blockIdx.x * 64;
    const int n0 = blockIdx.y * 64;
    const int rl = tid >> 4;
    const int c4 = (tid & 15) * 4;
    float acc[4][4] = {};

#pragma unroll
    for (int i = 0; i < 4; i++) {
        int r = rl + 16 * i;
        int gm = m0 + r;
        float4 v = make_float4(0.f, 0.f, 0.f, 0.f);
        if (gm < M) v = *(const float4*)&t[(size_t)gm * 64 + c4];
        ts[c4 + 0][r] = v.x; ts[c4 + 1][r] = v.y;
        ts[c4 + 2][r] = v.z; ts[c4 + 3][r] = v.w;
        float4 w = *(const float4*)&w2[(size_t)r * Nc + n0 + c4];
        *(float4*)&ws[r][c4] = w;
    }
    __syncthreads();
#pragma unroll 16
    for (int kk = 0; kk < 64; kk++) {
        float4 a = *(const float4*)&ts[kk][rl * 4];
        float4 b = *(const float4*)&ws[kk][c4];
        float ar[4] = {a.x, a.y, a.z, a.w};
        float bc[4] = {b.x, b.y, b.z, b.w};
#pragma unroll
        for (int r = 0; r < 4; r++)
#pragma unroll
            for (int c = 0; c < 4; c++)
                acc[r][c] = fmaf(ar[r], bc[c], acc[r][c]);
    }
    float4 bb = *(const float4*)&b2[n0 + c4];
    float bias[4] = {bb.x, bb.y, bb.z, bb.w};
#pragma unroll
    for (int r = 0; r < 4; r++) {
        int gm = m0 + rl * 4 + r;
        if (gm < M) {
            float4 o;
            o.x = acc[r][0] + bias[0];
            o.y = acc[r][1] + bias[1];
            o.z = acc[r][2] + bias[2];
            o.w = acc[r][3] + bias[3];
            *(float4*)&out[(size_t)gm * OS + n0 + c4] = o;
            ushort4 hq;
            hq.x = f2bf(o.x); hq.y = f2bf(o.y);
            hq.z = f2bf(o.z); hq.w = f2bf(o.w);
            *(ushort4*)&hb[(size_t)gm * Nc + n0 + c4] = hq;
        }
    }
}

// ---------------------------------------------------------------------------
// Aggregation: per-node max over incoming edges (CSR), wave per node.
// Gather table hb is dense bf16 [N, tstride]; this pass covers channels
// [choff, choff + 64*R); output f32 at `ostride` with same channel offset.
// Channel-split passes keep the gather slice L2/L3-resident.
// ---------------------------------------------------------------------------
template <int R>
__global__ void k_agg(const bfu* __restrict__ hb, float* __restrict__ aggr,
                      const int* __restrict__ rowptr, const int* __restrict__ colidx,
                      int N, int tstride, int ostride, int choff) {
    const int wid = (blockIdx.x * blockDim.x + threadIdx.x) >> 6;
    const int lane = threadIdx.x & 63;
    if (wid >= N) return;
    const int beg = rowptr[wid], end = rowptr[wid + 1];
    const int ch = choff + lane * R;

    float acc[R];
#pragma unroll
    for (int r = 0; r < R; r++) acc[r] = -INFINITY;

    int i = beg;
    for (; i + 4 <= end; i += 4) {
        int s0 = colidx[i + 0], s1 = colidx[i + 1];
        int s2 = colidx[i + 2], s3 = colidx[i + 3];
        const bfu* p0 = hb + (size_t)s0 * tstride + ch;
        const bfu* p1 = hb + (size_t)s1 * tstride + ch;
        const bfu* p2 = hb + (size_t)s2 * tstride + ch;
        const bfu* p3 = hb + (size_t)s3 * tstride + ch;
        if (R == 4) {
            ushort4 v0 = *(const ushort4*)p0;
            ushort4 v1 = *(const ushort4*)p1;
            ushort4 v2 = *(const ushort4*)p2;
            ushort4 v3 = *(const ushort4*)p3;
            acc[0] = fmaxf(acc[0], fmaxf(fmaxf(b2f(v0.x), b2f(v1.x)), fmaxf(b2f(v2.x), b2f(v3.x))));
            acc[1] = fmaxf(acc[1], fmaxf(fmaxf(b2f(v0.y), b2f(v1.y)), fmaxf(b2f(v2.y), b2f(v3.y))));
            acc[2] = fmaxf(acc[2], fmaxf(fmaxf(b2f(v0.z), b2f(v1.z)), fmaxf(b2f(v2.z), b2f(v3.z))));
            acc[3] = fmaxf(acc[3], fmaxf(fmaxf(b2f(v0.w), b2f(v1.w)), fmaxf(b2f(v2.w), b2f(v3.w))));
        } else if (R == 2) {
            ushort2 v0 = *(const ushort2*)p0;
            ushort2 v1 = *(const ushort2*)p1;
            ushort2 v2 = *(const ushort2*)p2;
            ushort2 v3 = *(const ushort2*)p3;
            acc[0] = fmaxf(acc[0], fmaxf(fmaxf(b2f(v0.x), b2f(v1.x)), fmaxf(b2f(v2.x), b2f(v3.x))));
            acc[1] = fmaxf(acc[1], fmaxf(fmaxf(b2f(v0.y), b2f(v1.y)), fmaxf(b2f(v2.y), b2f(v3.y))));
        } else {
            bfu v0 = *p0, v1 = *p1, v2 = *p2, v3 = *p3;
            acc[0] = fmaxf(acc[0], fmaxf(fmaxf(b2f(v0), b2f(v1)), fmaxf(b2f(v2), b2f(v3))));
        }
    }
    for (; i < end; i++) {
        int s = colidx[i];
        const bfu* p = hb + (size_t)s * tstride + ch;
        if (R == 4) {
            ushort4 v = *(const ushort4*)p;
            acc[0] = fmaxf(acc[0], b2f(v.x)); acc[1] = fmaxf(acc[1], b2f(v.y));
            acc[2] = fmaxf(acc[2], b2f(v.z)); acc[3] = fmaxf(acc[3], b2f(v.w));
        } else if (R == 2) {
            ushort2 v = *(const ushort2*)p;
            acc[0] = fmaxf(acc[0], b2f(v.x)); acc[1] = fmaxf(acc[1], b2f(v.y));
        } else {
            acc[0] = fmaxf(acc[0], b2f(*p));
        }
    }

    if (beg == end) {
#pragma unroll
        for (int r = 0; r < R; r++) acc[r] = 0.f;
    }
    float* q = aggr + (size_t)wid * ostride + ch;
#pragma unroll
    for (int r = 0; r < R; r++) q[r] = acc[r];
}

// ---------------------------------------------------------------------------
// Cluster max-pool: block per cluster, 256 thr x float2; 4-deep unrolled gather
// ---------------------------------------------------------------------------
__global__ void k_pool(const float* __restrict__ x3, const int* __restrict__ cptr,
                       const int* __restrict__ cidx, float* __restrict__ pooled) {
    int cl = blockIdx.x;
    int tid = threadIdx.x;
    int beg = cptr[cl], end = cptr[cl + 1];
    float ax = -INFINITY, ay = -INFINITY;
    int i = beg;
    for (; i + 4 <= end; i += 4) {
        int n0 = cidx[i + 0], n1 = cidx[i + 1];
        int n2 = cidx[i + 2], n3 = cidx[i + 3];
        float2 v0 = *(const float2*)&x3[(size_t)n0 * 512 + tid * 2];
        float2 v1 = *(const float2*)&x3[(size_t)n1 * 512 + tid * 2];
        float2 v2 = *(const float2*)&x3[(size_t)n2 * 512 + tid * 2];
        float2 v3 = *(const float2*)&x3[(size_t)n3 * 512 + tid * 2];
        ax = fmaxf(ax, fmaxf(fmaxf(v0.x, v1.x), fmaxf(v2.x, v3.x)));
        ay = fmaxf(ay, fmaxf(fmaxf(v0.y, v1.y), fmaxf(v2.y, v3.y)));
    }
    for (; i < end; i++) {
        int n = cidx[i];
        float2 v = *(const float2*)&x3[(size_t)n * 512 + tid * 2];
        ax = fmaxf(ax, v.x); ay = fmaxf(ay, v.y);
    }
    if (beg == end) { ax = 0.f; ay = 0.f; }
    float2 o; o.x = ax; o.y = ay;
    *(float2*)&pooled[(size_t)cl * 512 + tid * 2] = o;
}

// ---------------------------------------------------------------------------
// Column-wise sum of squares (axis 0), low-contention (64 blocks)
// ---------------------------------------------------------------------------
__global__ void k_sumsq(const float* __restrict__ pooled, float* __restrict__ sumsq, int NC) {
    int tid = threadIdx.x;
    float ax = 0.f, ay = 0.f;
    for (int r = blockIdx.x; r < NC; r += gridDim.x) {
        float2 v = *(const float2*)&pooled[(size_t)r * 512 + tid * 2];
        ax += v.x * v.x; ay += v.y * v.y;
    }
    atomicAdd(&sumsq[tid * 2 + 0], ax);
    atomicAdd(&sumsq[tid * 2 + 1], ay);
}

__global__ void k_scale(const float* __restrict__ pooled, const float* __restrict__ sumsq,
                        float* __restrict__ out, int total) {
    int i = blockIdx.x * blockDim.x + threadIdx.x;
    int base = i * 4;
    if (base < total) {
        float4 v = *(const float4*)&pooled[base];
        int col = base & 511;
        v.x /= (sqrtf(sumsq[col + 0]) + 1e-6f);
        v.y /= (sqrtf(sumsq[col + 1]) + 1e-6f);
        v.z /= (sqrtf(sumsq[col + 2]) + 1e-6f);
        v.w /= (sqrtf(sumsq[col + 3]) + 1e-6f);
        *(float4*)&out[base] = v;
    }
}

// ---------------------------------------------------------------------------
extern "C" void kernel_launch(void* const* d_in, const int* in_sizes, int n_in,
                              void* d_out, int out_size, void* d_ws, size_t ws_size,
                              hipStream_t stream) {
    const float* x0      = (const float*)d_in[0];
    const int*   ei      = (const int*)d_in[1];
    const int*   cluster = (const int*)d_in[2];
    const float* w1_[3] = {(const float*)d_in[3], (const float*)d_in[7],  (const float*)d_in[11]};
    const float* b1_[3] = {(const float*)d_in[4], (const float*)d_in[8],  (const float*)d_in[12]};
    const float* w2_[3] = {(const float*)d_in[5], (const float*)d_in[9],  (const float*)d_in[13]};
    const float* b2_[3] = {(const float*)d_in[6], (const float*)d_in[10], (const float*)d_in[14]};

    const int N  = in_sizes[2];       // 50000
    const int E  = in_sizes[1] / 2;   // 800000
    const int NC = 2500;
    float* out = (float*)d_out;

    char* p = (char*)d_ws;
    auto alloc = [&](size_t bytes) -> char* {
        char* r = p;
        p += (bytes + 255) & ~(size_t)255;
        return r;
    };
    float* x1     = (float*)alloc((size_t)N * 128 * 4);
    float* x2     = (float*)alloc((size_t)N * 256 * 4);
    float* x3     = (float*)alloc((size_t)N * 512 * 4);
    float* tbuf   = (float*)alloc((size_t)N * 64 * 4);
    bfu*   hb0    = (bfu*)alloc((size_t)N * 64 * 2);
    bfu*   hb1    = (bfu*)alloc((size_t)N * 128 * 2);
    bfu*   hb2    = (bfu*)alloc((size_t)N * 256 * 2);
    float* pooled = (float*)alloc((size_t)NC * 512 * 4);
    float* sumsq  = (float*)alloc(512 * 4);
    int*   deg    = (int*)alloc((size_t)(N + 1) * 4);
    int*   rowptr = (int*)alloc((size_t)(N + 1) * 4);
    int*   cursor = (int*)alloc((size_t)(N + 1) * 4);
    int*   colidx = (int*)alloc((size_t)E * 4);
    int*   cdeg   = (int*)alloc((size_t)(NC + 1) * 4);
    int*   cptr   = (int*)alloc((size_t)(NC + 1) * 4);
    int*   ccur   = (int*)alloc((size_t)(NC + 1) * 4);
    int*   cidx   = (int*)alloc((size_t)N * 4);
    int*   scn0   = (int*)alloc((size_t)N * 4);
    int*   scn1   = (int*)alloc((size_t)NC * 4);
    int*   bsum0  = (int*)alloc(256 * 4);
    int*   bsum1  = (int*)alloc(256 * 4);

    const int* src = ei;
    const int* dst = ei + E;

    k_zero3<<<(N + 255) / 256, 256, 0, stream>>>(deg, N, cdeg, NC, sumsq);

    // histograms
    k_hist<<<(E + 255) / 256, 256, 0, stream>>>(dst, E, deg);
    k_hist<<<(N + 255) / 256, 256, 0, stream>>>(cluster, N, cdeg);

    // hierarchical exclusive scan of both segments
    const int nb0 = (N + 255) / 256;
    const int nb1 = (NC + 255) / 256;
    k_scanA<<<dim3(nb0, 2), 256, 0, stream>>>(deg, N, cdeg, NC, scn0, scn1, bsum0, bsum1);
    k_scanB<<<1, 256, 0, stream>>>(bsum0, nb0, bsum1, nb1, rowptr, N, cptr, NC);
    k_scanC<<<dim3(nb0, 2), 256, 0, stream>>>(deg, N, cdeg, NC, scn0, scn1, bsum0, bsum1,
                                              rowptr, cursor, cptr, ccur);

    // scatters
    k_scatter_edges<<<(E + 255) / 256, 256, 0, stream>>>(dst, src, E, cursor, colidx);
    k_scatter_nodes<<<(N + 255) / 256, 256, 0, stream>>>(cluster, N, ccur, cidx);

    const int Mtiles = (N + 63) / 64;
    const int aggBlocks = (N * 64 + 255) / 256;

    // layer 0: c=64  (gather table 6.4MB -> single pass)
    k_mlp1<64><<<Mtiles, 256, 0, stream>>>(x0, w1_[0], b1_[0], tbuf, N);
    k_mlp2<<<dim3(Mtiles, 1), 256, 0, stream>>>(tbuf, w2_[0], b2_[0], x1, hb0, N, 64, 128);
    k_agg<1><<<aggBlocks, 256, 0, stream>>>(hb0, x1 + 64, rowptr, colidx, N, 64, 128, 0);

    // layer 1: c=128  (table 12.8MB -> 2 passes of 6.4MB slices)
    k_mlp1<128><<<Mtiles, 256, 0, stream>>>(x1, w1_[1], b1_[1], tbuf, N);
    k_mlp2<<<dim3(Mtiles, 2), 256, 0, stream>>>(tbuf, w2_[1], b2_[1], x2, hb1, N, 128, 256);
    k_agg<1><<<aggBlocks, 256, 0, stream>>>(hb1, x2 + 128, rowptr, colidx, N, 128, 256, 0);
    k_agg<1><<<aggBlocks, 256, 0, stream>>>(hb1, x2 + 128, rowptr, colidx, N, 128, 256, 64);

    // layer 2: c=256  (table 25.6MB -> 2 passes of 12.8MB slices)
    k_mlp1<256><<<Mtiles, 256, 0, stream>>>(x2, w1_[2], b1_[2], tbuf, N);
    k_mlp2<<<dim3(Mtiles, 4), 256, 0, stream>>>(tbuf, w2_[2], b2_[2], x3, hb2, N, 256, 512);
    k_agg<2><<<aggBlocks, 256, 0, stream>>>(hb2, x3 + 256, rowptr, colidx, N, 256, 512, 0);
    k_agg<2><<<aggBlocks, 256, 0, stream>>>(hb2, x3 + 256, rowptr, colidx, N, 256, 512, 128);

    // cluster max-pool + column norm
    k_pool<<<NC, 256, 0, stream>>>(x3, cptr, cidx, pooled);
    k_sumsq<<<64, 256, 0, stream>>>(pooled, sumsq, NC);
    k_scale<<<(out_size / 4 + 255) / 256, 256, 0, stream>>>(pooled, sumsq, out, out_size);
}

// Round 7
// 371.945 us; speedup vs baseline: 2.2427x; 1.2238x over previous
//
#include <hip/hip_runtime.h>
#include <math.h>

typedef unsigned short bfu;
typedef __attribute__((ext_vector_type(8))) short bf16x8;
typedef __attribute__((ext_vector_type(16))) float f32x16;

__device__ __forceinline__ float b2f(bfu u) {
    unsigned int x = ((unsigned int)u) << 16;
    return __uint_as_float(x);
}
__device__ __forceinline__ bfu f2bf(float f) {
    unsigned int u = __float_as_uint(f);
    unsigned int r = (u + 0x7FFFu + ((u >> 16) & 1u)) >> 16;
    return (bfu)r;
}

// ---------------------------------------------------------------------------
// fused zero: deg[N], cdeg[NC], sumsq[512]
// ---------------------------------------------------------------------------
__global__ void k_zero3(int* __restrict__ deg, int N, int* __restrict__ cdeg, int NC,
                        float* __restrict__ sumsq) {
    int i = blockIdx.x * blockDim.x + threadIdx.x;
    if (i < N) deg[i] = 0;
    if (i < NC) cdeg[i] = 0;
    if (i < 512) sumsq[i] = 0.f;
}

// ---------------------------------------------------------------------------
// CSR build: histogram -> hierarchical scan -> scatter
// ---------------------------------------------------------------------------
__global__ void k_hist(const int* __restrict__ keys, int n, int* __restrict__ deg) {
    int i = blockIdx.x * blockDim.x + threadIdx.x;
    if (i < n) atomicAdd(&deg[keys[i]], 1);
}

__global__ __launch_bounds__(256) void k_scanA(const int* __restrict__ deg, int N,
                                               const int* __restrict__ cdeg, int NC,
                                               int* __restrict__ scn0, int* __restrict__ scn1,
                                               int* __restrict__ bsum0, int* __restrict__ bsum1) {
    __shared__ int part[256];
    const int seg = blockIdx.y;
    const int n = seg ? NC : N;
    const int* d = seg ? cdeg : deg;
    int* scn = seg ? scn1 : scn0;
    int* bs  = seg ? bsum1 : bsum0;
    const int b = blockIdx.x;
    if (b * 256 >= n) return;
    const int t = threadIdx.x;
    const int i = b * 256 + t;
    int v = (i < n) ? d[i] : 0;
    part[t] = v;
    __syncthreads();
#pragma unroll
    for (int off = 1; off < 256; off <<= 1) {
        int cv = part[t];
        int u = (t >= off) ? part[t - off] : 0;
        __syncthreads();
        part[t] = cv + u;
        __syncthreads();
    }
    if (i < n) scn[i] = part[t];
    if (t == 255) bs[b] = part[255];
}

__global__ __launch_bounds__(256) void k_scanB(int* __restrict__ bsum0, int nb0,
                                               int* __restrict__ bsum1, int nb1,
                                               int* __restrict__ ptr0, int N,
                                               int* __restrict__ ptr1, int NC) {
    __shared__ int part[256];
    const int t = threadIdx.x;
    int v = (t < nb0) ? bsum0[t] : 0;
    part[t] = v;
    __syncthreads();
#pragma unroll
    for (int off = 1; off < 256; off <<= 1) {
        int cv = part[t];
        int u = (t >= off) ? part[t - off] : 0;
        __syncthreads();
        part[t] = cv + u;
        __syncthreads();
    }
    if (t < nb0) bsum0[t] = part[t] - v;
    if (t == 255) ptr0[N] = part[255];
    __syncthreads();
    v = (t < nb1) ? bsum1[t] : 0;
    part[t] = v;
    __syncthreads();
#pragma unroll
    for (int off = 1; off < 256; off <<= 1) {
        int cv = part[t];
        int u = (t >= off) ? part[t - off] : 0;
        __syncthreads();
        part[t] = cv + u;
        __syncthreads();
    }
    if (t < nb1) bsum1[t] = part[t] - v;
    if (t == 255) ptr1[NC] = part[255];
}

__global__ __launch_bounds__(256) void k_scanC(const int* __restrict__ deg, int N,
                                               const int* __restrict__ cdeg, int NC,
                                               const int* __restrict__ scn0, const int* __restrict__ scn1,
                                               const int* __restrict__ bsum0, const int* __restrict__ bsum1,
                                               int* __restrict__ ptr0, int* __restrict__ cur0,
                                               int* __restrict__ ptr1, int* __restrict__ cur1) {
    const int seg = blockIdx.y;
    const int n = seg ? NC : N;
    const int* d = seg ? cdeg : deg;
    const int* scn = seg ? scn1 : scn0;
    const int* bs  = seg ? bsum1 : bsum0;
    int* ptr = seg ? ptr1 : ptr0;
    int* cur = seg ? cur1 : cur0;
    const int b = blockIdx.x;
    if (b * 256 >= n) return;
    const int i = b * 256 + threadIdx.x;
    if (i < n) {
        int e = bs[b] + scn[i] - d[i];
        ptr[i] = e;
        cur[i] = e;
    }
}

__global__ void k_scatter_edges(const int* __restrict__ dst, const int* __restrict__ src,
                                int E, int* __restrict__ cur, int* __restrict__ colidx) {
    int e = blockIdx.x * blockDim.x + threadIdx.x;
    if (e < E) {
        int d = dst[e];
        int pos = atomicAdd(&cur[d], 1);
        colidx[pos] = src[e];
    }
}

__global__ void k_scatter_nodes(const int* __restrict__ key, int N,
                                int* __restrict__ cur, int* __restrict__ idx) {
    int i = blockIdx.x * blockDim.x + threadIdx.x;
    if (i < N) {
        int c = key[i];
        int pos = atomicAdd(&cur[c], 1);
        idx[pos] = i;
    }
}

// ---------------------------------------------------------------------------
// Prep: weight f32 [K][N] -> transposed hi/lo bf16 planes [N][K]
// ---------------------------------------------------------------------------
__global__ void k_prep(const float* __restrict__ w, int K, int Nw,
                       bfu* __restrict__ dhi, bfu* __restrict__ dlo) {
    int idx = blockIdx.x * blockDim.x + threadIdx.x;
    if (idx < K * Nw) {
        int k = idx / Nw, n = idx % Nw;
        float v = w[idx];
        bfu hi = f2bf(v);
        bfu lo = f2bf(v - b2f(hi));
        dhi[(size_t)n * K + k] = hi;
        dlo[(size_t)n * K + k] = lo;
    }
}

// x0 f32 [M][64] -> hi/lo planes (same layout)
__global__ void k_cvt(const float* __restrict__ x, int total,
                      bfu* __restrict__ dhi, bfu* __restrict__ dlo) {
    int i = blockIdx.x * blockDim.x + threadIdx.x;
    int base = i * 4;
    if (base < total) {
        float4 v = *(const float4*)&x[base];
        ushort4 h, l;
        h.x = f2bf(v.x); l.x = f2bf(v.x - b2f(h.x));
        h.y = f2bf(v.y); l.y = f2bf(v.y - b2f(h.y));
        h.z = f2bf(v.z); l.z = f2bf(v.z - b2f(h.z));
        h.w = f2bf(v.w); l.w = f2bf(v.w - b2f(h.w));
        *(ushort4*)&dhi[base] = h;
        *(ushort4*)&dlo[base] = l;
    }
}

// ---------------------------------------------------------------------------
// MFMA GEMM (split-bf16, 3-product): O = act(A @ B + bias)
//   A: hi/lo bf16 planes [M][K] row-major (row stride = K)
//   B: hi/lo bf16 planes [Nglobal][K] (pre-transposed), tile n0 = blockIdx.y*64
//   O: hi/lo bf16 planes, row stride OS, cols [n0, n0+64)
//   128x64 tile, 4 waves, each wave 32 rows x 64 cols via 2x mfma_32x32x16.
//   LDS XOR-swizzle: byte ^= (row&7)<<4 (rows are 128B).
// ---------------------------------------------------------------------------
__device__ __forceinline__ int swz(int row, int kb) {
    return (row * 128 + (kb ^ ((row & 7) << 4))) >> 1;  // ushort index
}

template <bool RELU>
__global__ __launch_bounds__(256) void k_gmfma(const bfu* __restrict__ Ahi, const bfu* __restrict__ Alo,
                                               const bfu* __restrict__ Bhi, const bfu* __restrict__ Blo,
                                               const float* __restrict__ bias,
                                               bfu* __restrict__ Ohi, bfu* __restrict__ Olo,
                                               int M, int K, int OS) {
    __shared__ __align__(16) bfu As[2][128 * 64];
    __shared__ __align__(16) bfu Bs[2][64 * 64];
    const int tid = threadIdx.x;
    const int wave = tid >> 6, lane = tid & 63;
    const int m0 = blockIdx.x * 128;
    const int n0 = blockIdx.y * 64;
    const int l31 = lane & 31;
    const int khalfb = (lane >> 5) * 16;  // byte offset of this lane's k-chunk

    f32x16 acc0, acc1;
#pragma unroll
    for (int i = 0; i < 16; i++) { acc0[i] = 0.f; acc1[i] = 0.f; }

    for (int k0 = 0; k0 < K; k0 += 64) {
        // stage A (2 planes x 4 rounds) and B (2 planes x 2 rounds)
#pragma unroll
        for (int p = 0; p < 2; p++) {
            const bfu* src = p ? Alo : Ahi;
#pragma unroll
            for (int i = 0; i < 4; i++) {
                int idx = i * 2048 + tid * 8;
                int row = idx >> 6;
                int ke = idx & 63;
                int gm = m0 + row; if (gm >= M) gm = M - 1;
                uint4 v = *(const uint4*)&src[(size_t)gm * K + k0 + ke];
                *(uint4*)&As[p][swz(row, ke * 2)] = v;
            }
        }
#pragma unroll
        for (int p = 0; p < 2; p++) {
            const bfu* src = p ? Blo : Bhi;
#pragma unroll
            for (int i = 0; i < 2; i++) {
                int idx = i * 2048 + tid * 8;
                int row = idx >> 6;
                int ke = idx & 63;
                uint4 v = *(const uint4*)&src[(size_t)(n0 + row) * K + k0 + ke];
                *(uint4*)&Bs[p][swz(row, ke * 2)] = v;
            }
        }
        __syncthreads();
        const int arow = wave * 32 + l31;
#pragma unroll
        for (int s = 0; s < 4; s++) {
            int kb = s * 32 + khalfb;
            bf16x8 ah = *(const bf16x8*)&As[0][swz(arow, kb)];
            bf16x8 al = *(const bf16x8*)&As[1][swz(arow, kb)];
            bf16x8 bh0 = *(const bf16x8*)&Bs[0][swz(l31, kb)];
            bf16x8 bl0 = *(const bf16x8*)&Bs[1][swz(l31, kb)];
            bf16x8 bh1 = *(const bf16x8*)&Bs[0][swz(32 + l31, kb)];
            bf16x8 bl1 = *(const bf16x8*)&Bs[1][swz(32 + l31, kb)];
            acc0 = __builtin_amdgcn_mfma_f32_32x32x16_bf16(ah, bh0, acc0, 0, 0, 0);
            acc0 = __builtin_amdgcn_mfma_f32_32x32x16_bf16(ah, bl0, acc0, 0, 0, 0);
            acc0 = __builtin_amdgcn_mfma_f32_32x32x16_bf16(al, bh0, acc0, 0, 0, 0);
            acc1 = __builtin_amdgcn_mfma_f32_32x32x16_bf16(ah, bh1, acc1, 0, 0, 0);
            acc1 = __builtin_amdgcn_mfma_f32_32x32x16_bf16(ah, bl1, acc1, 0, 0, 0);
            acc1 = __builtin_amdgcn_mfma_f32_32x32x16_bf16(al, bh1, acc1, 0, 0, 0);
        }
        __syncthreads();
    }

    // epilogue: C/D layout col=lane&31, row=(reg&3)+8*(reg>>2)+4*(lane>>5)
    float bc0 = bias[n0 + l31];
    float bc1 = bias[n0 + 32 + l31];
    const int rbase = m0 + wave * 32 + 4 * (lane >> 5);
#pragma unroll
    for (int r = 0; r < 16; r++) {
        int grow = rbase + (r & 3) + 8 * (r >> 2);
        if (grow < M) {
            float o0 = acc0[r] + bc0;
            float o1 = acc1[r] + bc1;
            if (RELU) { o0 = fmaxf(o0, 0.f); o1 = fmaxf(o1, 0.f); }
            bfu h0 = f2bf(o0), h1 = f2bf(o1);
            bfu lo0 = f2bf(o0 - b2f(h0)), lo1 = f2bf(o1 - b2f(h1));
            size_t base = (size_t)grow * OS + n0;
            Ohi[base + l31] = h0;
            Ohi[base + 32 + l31] = h1;
            Olo[base + l31] = lo0;
            Olo[base + 32 + l31] = lo1;
        }
    }
}

// ---------------------------------------------------------------------------
// Aggregation: per-node max over incoming edges (CSR), wave per node.
// Gather h-part (cols [0,64R)) of hi plane [N][stride]; write max (exact bf16)
// into cols [64R, 128R) of hi plane, zeros into lo plane.
// ---------------------------------------------------------------------------
template <int R>
__global__ void k_agg(const bfu* __restrict__ hplane, bfu* __restrict__ whi,
                      bfu* __restrict__ wlo,
                      const int* __restrict__ rowptr, const int* __restrict__ colidx,
                      int N, int stride) {
    const int wid = (blockIdx.x * blockDim.x + threadIdx.x) >> 6;
    const int lane = threadIdx.x & 63;
    if (wid >= N) return;
    const int beg = rowptr[wid], end = rowptr[wid + 1];
    const int ch = lane * R;

    float acc[R];
#pragma unroll
    for (int r = 0; r < R; r++) acc[r] = -INFINITY;

    int i = beg;
    for (; i + 4 <= end; i += 4) {
        int s0 = colidx[i + 0], s1 = colidx[i + 1];
        int s2 = colidx[i + 2], s3 = colidx[i + 3];
        const bfu* p0 = hplane + (size_t)s0 * stride + ch;
        const bfu* p1 = hplane + (size_t)s1 * stride + ch;
        const bfu* p2 = hplane + (size_t)s2 * stride + ch;
        const bfu* p3 = hplane + (size_t)s3 * stride + ch;
        if (R == 4) {
            ushort4 v0 = *(const ushort4*)p0;
            ushort4 v1 = *(const ushort4*)p1;
            ushort4 v2 = *(const ushort4*)p2;
            ushort4 v3 = *(const ushort4*)p3;
            acc[0] = fmaxf(acc[0], fmaxf(fmaxf(b2f(v0.x), b2f(v1.x)), fmaxf(b2f(v2.x), b2f(v3.x))));
            acc[1] = fmaxf(acc[1], fmaxf(fmaxf(b2f(v0.y), b2f(v1.y)), fmaxf(b2f(v2.y), b2f(v3.y))));
            acc[2] = fmaxf(acc[2], fmaxf(fmaxf(b2f(v0.z), b2f(v1.z)), fmaxf(b2f(v2.z), b2f(v3.z))));
            acc[3] = fmaxf(acc[3], fmaxf(fmaxf(b2f(v0.w), b2f(v1.w)), fmaxf(b2f(v2.w), b2f(v3.w))));
        } else if (R == 2) {
            ushort2 v0 = *(const ushort2*)p0;
            ushort2 v1 = *(const ushort2*)p1;
            ushort2 v2 = *(const ushort2*)p2;
            ushort2 v3 = *(const ushort2*)p3;
            acc[0] = fmaxf(acc[0], fmaxf(fmaxf(b2f(v0.x), b2f(v1.x)), fmaxf(b2f(v2.x), b2f(v3.x))));
            acc[1] = fmaxf(acc[1], fmaxf(fmaxf(b2f(v0.y), b2f(v1.y)), fmaxf(b2f(v2.y), b2f(v3.y))));
        } else {
            bfu v0 = *p0, v1 = *p1, v2 = *p2, v3 = *p3;
            acc[0] = fmaxf(acc[0], fmaxf(fmaxf(b2f(v0), b2f(v1)), fmaxf(b2f(v2), b2f(v3))));
        }
    }
    for (; i < end; i++) {
        int s = colidx[i];
        const bfu* p = hplane + (size_t)s * stride + ch;
        if (R == 4) {
            ushort4 v = *(const ushort4*)p;
            acc[0] = fmaxf(acc[0], b2f(v.x)); acc[1] = fmaxf(acc[1], b2f(v.y));
            acc[2] = fmaxf(acc[2], b2f(v.z)); acc[3] = fmaxf(acc[3], b2f(v.w));
        } else if (R == 2) {
            ushort2 v = *(const ushort2*)p;
            acc[0] = fmaxf(acc[0], b2f(v.x)); acc[1] = fmaxf(acc[1], b2f(v.y));
        } else {
            acc[0] = fmaxf(acc[0], b2f(*p));
        }
    }

    if (beg == end) {
#pragma unroll
        for (int r = 0; r < R; r++) acc[r] = 0.f;
    }
    size_t obase = (size_t)wid * stride + 64 * R + ch;
#pragma unroll
    for (int r = 0; r < R; r++) {
        whi[obase + r] = f2bf(acc[r]);  // exact (acc is a bf16 value or 0)
        wlo[obase + r] = 0;
    }
}

// ---------------------------------------------------------------------------
// Cluster max-pool from hi/lo planes [M][512]; 4-deep unrolled gather
// ---------------------------------------------------------------------------
__global__ void k_pool(const bfu* __restrict__ xhi, const bfu* __restrict__ xlo,
                       const int* __restrict__ cptr, const int* __restrict__ cidx,
                       float* __restrict__ pooled) {
    int cl = blockIdx.x;
    int tid = threadIdx.x;
    int beg = cptr[cl], end = cptr[cl + 1];
    float ax = -INFINITY, ay = -INFINITY;
    int i = beg;
    for (; i + 4 <= end; i += 4) {
        int n0 = cidx[i + 0], n1 = cidx[i + 1];
        int n2 = cidx[i + 2], n3 = cidx[i + 3];
        ushort2 h0 = *(const ushort2*)&xhi[(size_t)n0 * 512 + tid * 2];
        ushort2 l0 = *(const ushort2*)&xlo[(size_t)n0 * 512 + tid * 2];
        ushort2 h1 = *(const ushort2*)&xhi[(size_t)n1 * 512 + tid * 2];
        ushort2 l1 = *(const ushort2*)&xlo[(size_t)n1 * 512 + tid * 2];
        ushort2 h2 = *(const ushort2*)&xhi[(size_t)n2 * 512 + tid * 2];
        ushort2 l2 = *(const ushort2*)&xlo[(size_t)n2 * 512 + tid * 2];
        ushort2 h3 = *(const ushort2*)&xhi[(size_t)n3 * 512 + tid * 2];
        ushort2 l3 = *(const ushort2*)&xlo[(size_t)n3 * 512 + tid * 2];
        ax = fmaxf(ax, fmaxf(fmaxf(b2f(h0.x) + b2f(l0.x), b2f(h1.x) + b2f(l1.x)),
                             fmaxf(b2f(h2.x) + b2f(l2.x), b2f(h3.x) + b2f(l3.x))));
        ay = fmaxf(ay, fmaxf(fmaxf(b2f(h0.y) + b2f(l0.y), b2f(h1.y) + b2f(l1.y)),
                             fmaxf(b2f(h2.y) + b2f(l2.y), b2f(h3.y) + b2f(l3.y))));
    }
    for (; i < end; i++) {
        int n = cidx[i];
        ushort2 h = *(const ushort2*)&xhi[(size_t)n * 512 + tid * 2];
        ushort2 l = *(const ushort2*)&xlo[(size_t)n * 512 + tid * 2];
        ax = fmaxf(ax, b2f(h.x) + b2f(l.x));
        ay = fmaxf(ay, b2f(h.y) + b2f(l.y));
    }
    if (beg == end) { ax = 0.f; ay = 0.f; }
    float2 o; o.x = ax; o.y = ay;
    *(float2*)&pooled[(size_t)cl * 512 + tid * 2] = o;
}

// ---------------------------------------------------------------------------
// Column-wise sum of squares (axis 0), low-contention (64 blocks)
// ---------------------------------------------------------------------------
__global__ void k_sumsq(const float* __restrict__ pooled, float* __restrict__ sumsq, int NC) {
    int tid = threadIdx.x;
    float ax = 0.f, ay = 0.f;
    for (int r = blockIdx.x; r < NC; r += gridDim.x) {
        float2 v = *(const float2*)&pooled[(size_t)r * 512 + tid * 2];
        ax += v.x * v.x; ay += v.y * v.y;
    }
    atomicAdd(&sumsq[tid * 2 + 0], ax);
    atomicAdd(&sumsq[tid * 2 + 1], ay);
}

__global__ void k_scale(const float* __restrict__ pooled, const float* __restrict__ sumsq,
                        float* __restrict__ out, int total) {
    int i = blockIdx.x * blockDim.x + threadIdx.x;
    int base = i * 4;
    if (base < total) {
        float4 v = *(const float4*)&pooled[base];
        int col = base & 511;
        v.x /= (sqrtf(sumsq[col + 0]) + 1e-6f);
        v.y /= (sqrtf(sumsq[col + 1]) + 1e-6f);
        v.z /= (sqrtf(sumsq[col + 2]) + 1e-6f);
        v.w /= (sqrtf(sumsq[col + 3]) + 1e-6f);
        *(float4*)&out[base] = v;
    }
}

// ---------------------------------------------------------------------------
extern "C" void kernel_launch(void* const* d_in, const int* in_sizes, int n_in,
                              void* d_out, int out_size, void* d_ws, size_t ws_size,
                              hipStream_t stream) {
    const float* x0      = (const float*)d_in[0];
    const int*   ei      = (const int*)d_in[1];
    const int*   cluster = (const int*)d_in[2];
    const float* w1_[3] = {(const float*)d_in[3], (const float*)d_in[7],  (const float*)d_in[11]};
    const float* b1_[3] = {(const float*)d_in[4], (const float*)d_in[8],  (const float*)d_in[12]};
    const float* w2_[3] = {(const float*)d_in[5], (const float*)d_in[9],  (const float*)d_in[13]};
    const float* b2_[3] = {(const float*)d_in[6], (const float*)d_in[10], (const float*)d_in[14]};

    const int N  = in_sizes[2];       // 50000
    const int E  = in_sizes[1] / 2;   // 800000
    const int NC = 2500;
    float* out = (float*)d_out;

    char* p = (char*)d_ws;
    auto alloc = [&](size_t bytes) -> char* {
        char* r = p;
        p += (bytes + 255) & ~(size_t)255;
        return r;
    };
    // activation hi/lo bf16 planes
    bfu* X0hi = (bfu*)alloc((size_t)N * 64 * 2);
    bfu* X0lo = (bfu*)alloc((size_t)N * 64 * 2);
    bfu* X1hi = (bfu*)alloc((size_t)N * 128 * 2);
    bfu* X1lo = (bfu*)alloc((size_t)N * 128 * 2);
    bfu* X2hi = (bfu*)alloc((size_t)N * 256 * 2);
    bfu* X2lo = (bfu*)alloc((size_t)N * 256 * 2);
    bfu* X3hi = (bfu*)alloc((size_t)N * 512 * 2);
    bfu* X3lo = (bfu*)alloc((size_t)N * 512 * 2);
    bfu* tbhi = (bfu*)alloc((size_t)N * 64 * 2);
    bfu* tblo = (bfu*)alloc((size_t)N * 64 * 2);
    // transposed weight hi/lo planes
    bfu* w1t_hi[3]; bfu* w1t_lo[3]; bfu* w2t_hi[3]; bfu* w2t_lo[3];
    const int Ks[3] = {64, 128, 256};
    for (int l = 0; l < 3; l++) {
        w1t_hi[l] = (bfu*)alloc((size_t)64 * Ks[l] * 2);
        w1t_lo[l] = (bfu*)alloc((size_t)64 * Ks[l] * 2);
        w2t_hi[l] = (bfu*)alloc((size_t)Ks[l] * 64 * 2);
        w2t_lo[l] = (bfu*)alloc((size_t)Ks[l] * 64 * 2);
    }
    float* pooled = (float*)alloc((size_t)NC * 512 * 4);
    float* sumsq  = (float*)alloc(512 * 4);
    int*   deg    = (int*)alloc((size_t)(N + 1) * 4);
    int*   rowptr = (int*)alloc((size_t)(N + 1) * 4);
    int*   cursor = (int*)alloc((size_t)(N + 1) * 4);
    int*   colidx = (int*)alloc((size_t)E * 4);
    int*   cdeg   = (int*)alloc((size_t)(NC + 1) * 4);
    int*   cptr   = (int*)alloc((size_t)(NC + 1) * 4);
    int*   ccur   = (int*)alloc((size_t)(NC + 1) * 4);
    int*   cidx   = (int*)alloc((size_t)N * 4);
    int*   scn0   = (int*)alloc((size_t)N * 4);
    int*   scn1   = (int*)alloc((size_t)NC * 4);
    int*   bsum0  = (int*)alloc(256 * 4);
    int*   bsum1  = (int*)alloc(256 * 4);

    const int* src = ei;
    const int* dst = ei + E;

    k_zero3<<<(N + 255) / 256, 256, 0, stream>>>(deg, N, cdeg, NC, sumsq);

    // histograms
    k_hist<<<(E + 255) / 256, 256, 0, stream>>>(dst, E, deg);
    k_hist<<<(N + 255) / 256, 256, 0, stream>>>(cluster, N, cdeg);

    // hierarchical exclusive scan of both segments
    const int nb0 = (N + 255) / 256;
    const int nb1 = (NC + 255) / 256;
    k_scanA<<<dim3(nb0, 2), 256, 0, stream>>>(deg, N, cdeg, NC, scn0, scn1, bsum0, bsum1);
    k_scanB<<<1, 256, 0, stream>>>(bsum0, nb0, bsum1, nb1, rowptr, N, cptr, NC);
    k_scanC<<<dim3(nb0, 2), 256, 0, stream>>>(deg, N, cdeg, NC, scn0, scn1, bsum0, bsum1,
                                              rowptr, cursor, cptr, ccur);

    // scatters
    k_scatter_edges<<<(E + 255) / 256, 256, 0, stream>>>(dst, src, E, cursor, colidx);
    k_scatter_nodes<<<(N + 255) / 256, 256, 0, stream>>>(cluster, N, ccur, cidx);

    // input + weight conversion to bf16 hi/lo
    k_cvt<<<(N * 64 / 4 + 255) / 256, 256, 0, stream>>>(x0, N * 64, X0hi, X0lo);
    for (int l = 0; l < 3; l++) {
        k_prep<<<(Ks[l] * 64 + 255) / 256, 256, 0, stream>>>(w1_[l], Ks[l], 64, w1t_hi[l], w1t_lo[l]);
        k_prep<<<(64 * Ks[l] + 255) / 256, 256, 0, stream>>>(w2_[l], 64, Ks[l], w2t_hi[l], w2t_lo[l]);
    }

    const int Mt = (N + 127) / 128;
    const int aggBlocks = (N * 64 + 255) / 256;

    // layer 0: c=64
    k_gmfma<true><<<dim3(Mt, 1), 256, 0, stream>>>(X0hi, X0lo, w1t_hi[0], w1t_lo[0], b1_[0], tbhi, tblo, N, 64, 64);
    k_gmfma<false><<<dim3(Mt, 1), 256, 0, stream>>>(tbhi, tblo, w2t_hi[0], w2t_lo[0], b2_[0], X1hi, X1lo, N, 64, 128);
    k_agg<1><<<aggBlocks, 256, 0, stream>>>(X1hi, X1hi, X1lo, rowptr, colidx, N, 128);

    // layer 1: c=128
    k_gmfma<true><<<dim3(Mt, 1), 256, 0, stream>>>(X1hi, X1lo, w1t_hi[1], w1t_lo[1], b1_[1], tbhi, tblo, N, 128, 64);
    k_gmfma<false><<<dim3(Mt, 2), 256, 0, stream>>>(tbhi, tblo, w2t_hi[1], w2t_lo[1], b2_[1], X2hi, X2lo, N, 64, 256);
    k_agg<2><<<aggBlocks, 256, 0, stream>>>(X2hi, X2hi, X2lo, rowptr, colidx, N, 256);

    // layer 2: c=256
    k_gmfma<true><<<dim3(Mt, 1), 256, 0, stream>>>(X2hi, X2lo, w1t_hi[2], w1t_lo[2], b1_[2], tbhi, tblo, N, 256, 64);
    k_gmfma<false><<<dim3(Mt, 4), 256, 0, stream>>>(tbhi, tblo, w2t_hi[2], w2t_lo[2], b2_[2], X3hi, X3lo, N, 64, 512);
    k_agg<4><<<aggBlocks, 256, 0, stream>>>(X3hi, X3hi, X3lo, rowptr, colidx, N, 512);

    // cluster max-pool + column norm
    k_pool<<<NC, 256, 0, stream>>>(X3hi, X3lo, cptr, cidx, pooled);
    k_sumsq<<<64, 256, 0, stream>>>(pooled, sumsq, NC);
    k_scale<<<(out_size / 4 + 255) / 256, 256, 0, stream>>>(pooled, sumsq, out, out_size);
}

// Round 8
// 354.282 us; speedup vs baseline: 2.3546x; 1.0499x over previous
//
#include <hip/hip_runtime.h>
#include <math.h>

typedef unsigned short bfu;
typedef __attribute__((ext_vector_type(8))) short bf16x8;
typedef __attribute__((ext_vector_type(16))) float f32x16;

__device__ __forceinline__ float b2f(bfu u) {
    unsigned int x = ((unsigned int)u) << 16;
    return __uint_as_float(x);
}
__device__ __forceinline__ bfu f2bf(float f) {
    unsigned int u = __float_as_uint(f);
    unsigned int r = (u + 0x7FFFu + ((u >> 16) & 1u)) >> 16;
    return (bfu)r;
}

// ---------------------------------------------------------------------------
// fused zero: deg[N], cdeg[NC], sumsq[512]
// ---------------------------------------------------------------------------
__global__ void k_zero3(int* __restrict__ deg, int N, int* __restrict__ cdeg, int NC,
                        float* __restrict__ sumsq) {
    int i = blockIdx.x * blockDim.x + threadIdx.x;
    if (i < N) deg[i] = 0;
    if (i < NC) cdeg[i] = 0;
    if (i < 512) sumsq[i] = 0.f;
}

// ---------------------------------------------------------------------------
// fused histograms: edge-dst -> deg[N], cluster -> cdeg[NC]
// ---------------------------------------------------------------------------
__global__ void k_hist2(const int* __restrict__ dst, int E, int* __restrict__ deg,
                        const int* __restrict__ cluster, int N, int* __restrict__ cdeg) {
    int i = blockIdx.x * blockDim.x + threadIdx.x;
    if (i < E) atomicAdd(&deg[dst[i]], 1);
    if (i < N) atomicAdd(&cdeg[cluster[i]], 1);
}

__global__ __launch_bounds__(256) void k_scanA(const int* __restrict__ deg, int N,
                                               const int* __restrict__ cdeg, int NC,
                                               int* __restrict__ scn0, int* __restrict__ scn1,
                                               int* __restrict__ bsum0, int* __restrict__ bsum1) {
    __shared__ int part[256];
    const int seg = blockIdx.y;
    const int n = seg ? NC : N;
    const int* d = seg ? cdeg : deg;
    int* scn = seg ? scn1 : scn0;
    int* bs  = seg ? bsum1 : bsum0;
    const int b = blockIdx.x;
    if (b * 256 >= n) return;
    const int t = threadIdx.x;
    const int i = b * 256 + t;
    int v = (i < n) ? d[i] : 0;
    part[t] = v;
    __syncthreads();
#pragma unroll
    for (int off = 1; off < 256; off <<= 1) {
        int cv = part[t];
        int u = (t >= off) ? part[t - off] : 0;
        __syncthreads();
        part[t] = cv + u;
        __syncthreads();
    }
    if (i < n) scn[i] = part[t];
    if (t == 255) bs[b] = part[255];
}

__global__ __launch_bounds__(256) void k_scanB(int* __restrict__ bsum0, int nb0,
                                               int* __restrict__ bsum1, int nb1,
                                               int* __restrict__ ptr0, int N,
                                               int* __restrict__ ptr1, int NC) {
    __shared__ int part[256];
    const int t = threadIdx.x;
    int v = (t < nb0) ? bsum0[t] : 0;
    part[t] = v;
    __syncthreads();
#pragma unroll
    for (int off = 1; off < 256; off <<= 1) {
        int cv = part[t];
        int u = (t >= off) ? part[t - off] : 0;
        __syncthreads();
        part[t] = cv + u;
        __syncthreads();
    }
    if (t < nb0) bsum0[t] = part[t] - v;
    if (t == 255) ptr0[N] = part[255];
    __syncthreads();
    v = (t < nb1) ? bsum1[t] : 0;
    part[t] = v;
    __syncthreads();
#pragma unroll
    for (int off = 1; off < 256; off <<= 1) {
        int cv = part[t];
        int u = (t >= off) ? part[t - off] : 0;
        __syncthreads();
        part[t] = cv + u;
        __syncthreads();
    }
    if (t < nb1) bsum1[t] = part[t] - v;
    if (t == 255) ptr1[NC] = part[255];
}

__global__ __launch_bounds__(256) void k_scanC(const int* __restrict__ deg, int N,
                                               const int* __restrict__ cdeg, int NC,
                                               const int* __restrict__ scn0, const int* __restrict__ scn1,
                                               const int* __restrict__ bsum0, const int* __restrict__ bsum1,
                                               int* __restrict__ ptr0, int* __restrict__ cur0,
                                               int* __restrict__ ptr1, int* __restrict__ cur1) {
    const int seg = blockIdx.y;
    const int n = seg ? NC : N;
    const int* d = seg ? cdeg : deg;
    const int* scn = seg ? scn1 : scn0;
    const int* bs  = seg ? bsum1 : bsum0;
    int* ptr = seg ? ptr1 : ptr0;
    int* cur = seg ? cur1 : cur0;
    const int b = blockIdx.x;
    if (b * 256 >= n) return;
    const int i = b * 256 + threadIdx.x;
    if (i < n) {
        int e = bs[b] + scn[i] - d[i];
        ptr[i] = e;
        cur[i] = e;
    }
}

// ---------------------------------------------------------------------------
// fused scatters: edges -> colidx, nodes -> cidx
// ---------------------------------------------------------------------------
__global__ void k_scatter2(const int* __restrict__ dst, const int* __restrict__ src, int E,
                           int* __restrict__ cur, int* __restrict__ colidx,
                           const int* __restrict__ cluster, int N,
                           int* __restrict__ ccur, int* __restrict__ cidx) {
    int i = blockIdx.x * blockDim.x + threadIdx.x;
    if (i < E) {
        int d = dst[i];
        int pos = atomicAdd(&cur[d], 1);
        colidx[pos] = src[i];
    }
    if (i < N) {
        int c = cluster[i];
        int pos = atomicAdd(&ccur[c], 1);
        cidx[pos] = i;
    }
}

// ---------------------------------------------------------------------------
// fused prep: 6 weights f32 [K][N] -> transposed hi/lo planes [N][K]  (y=0..5)
//             + x0 f32 -> hi/lo planes (y=6)
// ---------------------------------------------------------------------------
struct P6 {
    const float* w[6];
    bfu* hi[6];
    bfu* lo[6];
    int K[6];
    int Nw[6];
    const float* x0;
    bfu* xhi; bfu* xlo;
    int xtotal;
};

__global__ __launch_bounds__(256) void k_prep_all(P6 a) {
    const int j = blockIdx.y;
    if (j < 6) {
        const int total = a.K[j] * a.Nw[j];
        const float* w = a.w[j];
        bfu* dhi = a.hi[j];
        bfu* dlo = a.lo[j];
        const int K = a.K[j], Nw = a.Nw[j];
        for (int idx = blockIdx.x * 256 + threadIdx.x; idx < total; idx += gridDim.x * 256) {
            int k = idx / Nw, n = idx % Nw;
            float v = w[idx];
            bfu hi = f2bf(v);
            bfu lo = f2bf(v - b2f(hi));
            dhi[n * K + k] = hi;
            dlo[n * K + k] = lo;
        }
    } else {
        for (int i = blockIdx.x * 256 + threadIdx.x; i * 4 < a.xtotal; i += gridDim.x * 256) {
            int base = i * 4;
            float4 v = *(const float4*)&a.x0[base];
            ushort4 h, l;
            h.x = f2bf(v.x); l.x = f2bf(v.x - b2f(h.x));
            h.y = f2bf(v.y); l.y = f2bf(v.y - b2f(h.y));
            h.z = f2bf(v.z); l.z = f2bf(v.z - b2f(h.z));
            h.w = f2bf(v.w); l.w = f2bf(v.w - b2f(h.w));
            *(ushort4*)&a.xhi[base] = h;
            *(ushort4*)&a.xlo[base] = l;
        }
    }
}

// ---------------------------------------------------------------------------
// MFMA GEMM (split-bf16, 3-product): O = act(A @ B + bias)
//   A: hi/lo bf16 planes [M][K] row-major. For k0 >= Kzero the lo plane is
//   structurally zero (aggregated half) -> skip Alo staging and al-product.
//   B: hi/lo bf16 planes [Nglobal][K] (pre-transposed), tile n0 = blockIdx.y*64
//   O: hi/lo bf16 planes, row stride OS, cols [n0, n0+64)
//   128x64 tile, 4 waves, LDS XOR-swizzle byte ^= (row&7)<<4.
// ---------------------------------------------------------------------------
__device__ __forceinline__ int swz(int row, int kb) {
    return (row * 128 + (kb ^ ((row & 7) << 4))) >> 1;  // ushort index
}

template <bool RELU>
__global__ __launch_bounds__(256) void k_gmfma(const bfu* __restrict__ Ahi, const bfu* __restrict__ Alo,
                                               const bfu* __restrict__ Bhi, const bfu* __restrict__ Blo,
                                               const float* __restrict__ bias,
                                               bfu* __restrict__ Ohi, bfu* __restrict__ Olo,
                                               int M, int K, int OS, int Kzero) {
    __shared__ __align__(16) bfu As[2][128 * 64];
    __shared__ __align__(16) bfu Bs[2][64 * 64];
    const int tid = threadIdx.x;
    const int wave = tid >> 6, lane = tid & 63;
    const int m0 = blockIdx.x * 128;
    const int n0 = blockIdx.y * 64;
    const int l31 = lane & 31;
    const int khalfb = (lane >> 5) * 16;  // byte offset of this lane's k-chunk

    f32x16 acc0, acc1;
#pragma unroll
    for (int i = 0; i < 16; i++) { acc0[i] = 0.f; acc1[i] = 0.f; }

    for (int k0 = 0; k0 < K; k0 += 64) {
        const bool full3 = (k0 < Kzero);
        // stage A hi plane (4 rounds)
#pragma unroll
        for (int i = 0; i < 4; i++) {
            int idx = i * 2048 + tid * 8;
            int row = idx >> 6;
            int ke = idx & 63;
            int gm = m0 + row; if (gm >= M) gm = M - 1;
            uint4 v = *(const uint4*)&Ahi[(size_t)gm * K + k0 + ke];
            *(uint4*)&As[0][swz(row, ke * 2)] = v;
        }
        // stage A lo plane only where nonzero
        if (full3) {
#pragma unroll
            for (int i = 0; i < 4; i++) {
                int idx = i * 2048 + tid * 8;
                int row = idx >> 6;
                int ke = idx & 63;
                int gm = m0 + row; if (gm >= M) gm = M - 1;
                uint4 v = *(const uint4*)&Alo[(size_t)gm * K + k0 + ke];
                *(uint4*)&As[1][swz(row, ke * 2)] = v;
            }
        }
#pragma unroll
        for (int p = 0; p < 2; p++) {
            const bfu* src = p ? Blo : Bhi;
#pragma unroll
            for (int i = 0; i < 2; i++) {
                int idx = i * 2048 + tid * 8;
                int row = idx >> 6;
                int ke = idx & 63;
                uint4 v = *(const uint4*)&src[(size_t)(n0 + row) * K + k0 + ke];
                *(uint4*)&Bs[p][swz(row, ke * 2)] = v;
            }
        }
        __syncthreads();
        const int arow = wave * 32 + l31;
#pragma unroll
        for (int s = 0; s < 4; s++) {
            int kb = s * 32 + khalfb;
            bf16x8 ah = *(const bf16x8*)&As[0][swz(arow, kb)];
            bf16x8 bh0 = *(const bf16x8*)&Bs[0][swz(l31, kb)];
            bf16x8 bl0 = *(const bf16x8*)&Bs[1][swz(l31, kb)];
            bf16x8 bh1 = *(const bf16x8*)&Bs[0][swz(32 + l31, kb)];
            bf16x8 bl1 = *(const bf16x8*)&Bs[1][swz(32 + l31, kb)];
            acc0 = __builtin_amdgcn_mfma_f32_32x32x16_bf16(ah, bh0, acc0, 0, 0, 0);
            acc0 = __builtin_amdgcn_mfma_f32_32x32x16_bf16(ah, bl0, acc0, 0, 0, 0);
            acc1 = __builtin_amdgcn_mfma_f32_32x32x16_bf16(ah, bh1, acc1, 0, 0, 0);
            acc1 = __builtin_amdgcn_mfma_f32_32x32x16_bf16(ah, bl1, acc1, 0, 0, 0);
            if (full3) {
                bf16x8 al = *(const bf16x8*)&As[1][swz(arow, kb)];
                acc0 = __builtin_amdgcn_mfma_f32_32x32x16_bf16(al, bh0, acc0, 0, 0, 0);
                acc1 = __builtin_amdgcn_mfma_f32_32x32x16_bf16(al, bh1, acc1, 0, 0, 0);
            }
        }
        __syncthreads();
    }

    // epilogue: C/D layout col=lane&31, row=(reg&3)+8*(reg>>2)+4*(lane>>5)
    float bc0 = bias[n0 + l31];
    float bc1 = bias[n0 + 32 + l31];
    const int rbase = m0 + wave * 32 + 4 * (lane >> 5);
#pragma unroll
    for (int r = 0; r < 16; r++) {
        int grow = rbase + (r & 3) + 8 * (r >> 2);
        if (grow < M) {
            float o0 = acc0[r] + bc0;
            float o1 = acc1[r] + bc1;
            if (RELU) { o0 = fmaxf(o0, 0.f); o1 = fmaxf(o1, 0.f); }
            bfu h0 = f2bf(o0), h1 = f2bf(o1);
            bfu lo0 = f2bf(o0 - b2f(h0)), lo1 = f2bf(o1 - b2f(h1));
            size_t base = (size_t)grow * OS + n0;
            Ohi[base + l31] = h0;
            Ohi[base + 32 + l31] = h1;
            Olo[base + l31] = lo0;
            Olo[base + 32 + l31] = lo1;
        }
    }
}

// ---------------------------------------------------------------------------
// Aggregation: per-node max over incoming edges (CSR), wave per node.
// Gather h-part (cols [0,64R)) of hi plane [N][stride]; write bf16 max into
// cols [64R, 128R) of hi plane. Lo plane of aggr half is structurally zero
// (never written; consumers skip it). 8-deep ILP, 32-bit addressing.
// ---------------------------------------------------------------------------
template <int R>
__device__ __forceinline__ void gmax(const bfu* __restrict__ p, float* acc) {
    if (R == 4) {
        ushort4 v = *(const ushort4*)p;
        acc[0] = fmaxf(acc[0], b2f(v.x)); acc[1] = fmaxf(acc[1], b2f(v.y));
        acc[2] = fmaxf(acc[2], b2f(v.z)); acc[3] = fmaxf(acc[3], b2f(v.w));
    } else if (R == 2) {
        ushort2 v = *(const ushort2*)p;
        acc[0] = fmaxf(acc[0], b2f(v.x)); acc[1] = fmaxf(acc[1], b2f(v.y));
    } else {
        acc[0] = fmaxf(acc[0], b2f(*p));
    }
}

template <int R>
__global__ void k_agg(const bfu* __restrict__ hplane, bfu* __restrict__ whi,
                      const int* __restrict__ rowptr, const int* __restrict__ colidx,
                      int N, int stride) {
    const int wid = (blockIdx.x * blockDim.x + threadIdx.x) >> 6;
    const int lane = threadIdx.x & 63;
    if (wid >= N) return;
    const int beg = rowptr[wid], end = rowptr[wid + 1];
    const int ch = lane * R;

    float acc[R];
#pragma unroll
    for (int r = 0; r < R; r++) acc[r] = -INFINITY;

    int i = beg;
    for (; i + 8 <= end; i += 8) {
        int off[8];
#pragma unroll
        for (int u = 0; u < 8; u++) off[u] = colidx[i + u] * stride + ch;
#pragma unroll
        for (int u = 0; u < 8; u++) gmax<R>(hplane + off[u], acc);
    }
    for (; i + 2 <= end; i += 2) {
        int o0 = colidx[i] * stride + ch;
        int o1 = colidx[i + 1] * stride + ch;
        gmax<R>(hplane + o0, acc);
        gmax<R>(hplane + o1, acc);
    }
    if (i < end) gmax<R>(hplane + colidx[i] * stride + ch, acc);

    if (beg == end) {
#pragma unroll
        for (int r = 0; r < R; r++) acc[r] = 0.f;
    }
    int obase = wid * stride + 64 * R + ch;
#pragma unroll
    for (int r = 0; r < R; r++) whi[obase + r] = f2bf(acc[r]);
}

// ---------------------------------------------------------------------------
// Cluster max-pool from hi/lo planes [M][512]; lo only valid for cols < 256.
// ---------------------------------------------------------------------------
__device__ __forceinline__ float2 rowval(const bfu* __restrict__ xhi, const bfu* __restrict__ xlo,
                                         int n, int tid, bool rl) {
    ushort2 h = *(const ushort2*)&xhi[n * 512 + tid * 2];
    float x = b2f(h.x), y = b2f(h.y);
    if (rl) {
        ushort2 l = *(const ushort2*)&xlo[n * 512 + tid * 2];
        x += b2f(l.x); y += b2f(l.y);
    }
    float2 r; r.x = x; r.y = y;
    return r;
}

__global__ void k_pool(const bfu* __restrict__ xhi, const bfu* __restrict__ xlo,
                       const int* __restrict__ cptr, const int* __restrict__ cidx,
                       float* __restrict__ pooled) {
    int cl = blockIdx.x;
    int tid = threadIdx.x;
    const bool rl = (tid < 128);  // cols < 256 have a lo plane; aggr half lo==0
    int beg = cptr[cl], end = cptr[cl + 1];
    float ax = -INFINITY, ay = -INFINITY;
    int i = beg;
    for (; i + 4 <= end; i += 4) {
        float2 v0 = rowval(xhi, xlo, cidx[i + 0], tid, rl);
        float2 v1 = rowval(xhi, xlo, cidx[i + 1], tid, rl);
        float2 v2 = rowval(xhi, xlo, cidx[i + 2], tid, rl);
        float2 v3 = rowval(xhi, xlo, cidx[i + 3], tid, rl);
        ax = fmaxf(ax, fmaxf(fmaxf(v0.x, v1.x), fmaxf(v2.x, v3.x)));
        ay = fmaxf(ay, fmaxf(fmaxf(v0.y, v1.y), fmaxf(v2.y, v3.y)));
    }
    for (; i < end; i++) {
        float2 v = rowval(xhi, xlo, cidx[i], tid, rl);
        ax = fmaxf(ax, v.x); ay = fmaxf(ay, v.y);
    }
    if (beg == end) { ax = 0.f; ay = 0.f; }
    float2 o; o.x = ax; o.y = ay;
    *(float2*)&pooled[(size_t)cl * 512 + tid * 2] = o;
}

// ---------------------------------------------------------------------------
// Column-wise sum of squares (axis 0), low-contention (64 blocks)
// ---------------------------------------------------------------------------
__global__ void k_sumsq(const float* __restrict__ pooled, float* __restrict__ sumsq, int NC) {
    int tid = threadIdx.x;
    float ax = 0.f, ay = 0.f;
    for (int r = blockIdx.x; r < NC; r += gridDim.x) {
        float2 v = *(const float2*)&pooled[(size_t)r * 512 + tid * 2];
        ax += v.x * v.x; ay += v.y * v.y;
    }
    atomicAdd(&sumsq[tid * 2 + 0], ax);
    atomicAdd(&sumsq[tid * 2 + 1], ay);
}

__global__ void k_scale(const float* __restrict__ pooled, const float* __restrict__ sumsq,
                        float* __restrict__ out, int total) {
    int i = blockIdx.x * blockDim.x + threadIdx.x;
    int base = i * 4;
    if (base < total) {
        float4 v = *(const float4*)&pooled[base];
        int col = base & 511;
        v.x /= (sqrtf(sumsq[col + 0]) + 1e-6f);
        v.y /= (sqrtf(sumsq[col + 1]) + 1e-6f);
        v.z /= (sqrtf(sumsq[col + 2]) + 1e-6f);
        v.w /= (sqrtf(sumsq[col + 3]) + 1e-6f);
        *(float4*)&out[base] = v;
    }
}

// ---------------------------------------------------------------------------
extern "C" void kernel_launch(void* const* d_in, const int* in_sizes, int n_in,
                              void* d_out, int out_size, void* d_ws, size_t ws_size,
                              hipStream_t stream) {
    const float* x0      = (const float*)d_in[0];
    const int*   ei      = (const int*)d_in[1];
    const int*   cluster = (const int*)d_in[2];
    const float* w1_[3] = {(const float*)d_in[3], (const float*)d_in[7],  (const float*)d_in[11]};
    const float* b1_[3] = {(const float*)d_in[4], (const float*)d_in[8],  (const float*)d_in[12]};
    const float* w2_[3] = {(const float*)d_in[5], (const float*)d_in[9],  (const float*)d_in[13]};
    const float* b2_[3] = {(const float*)d_in[6], (const float*)d_in[10], (const float*)d_in[14]};

    const int N  = in_sizes[2];       // 50000
    const int E  = in_sizes[1] / 2;   // 800000
    const int NC = 2500;
    float* out = (float*)d_out;

    char* p = (char*)d_ws;
    auto alloc = [&](size_t bytes) -> char* {
        char* r = p;
        p += (bytes + 255) & ~(size_t)255;
        return r;
    };
    // activation hi/lo bf16 planes
    bfu* X0hi = (bfu*)alloc((size_t)N * 64 * 2);
    bfu* X0lo = (bfu*)alloc((size_t)N * 64 * 2);
    bfu* X1hi = (bfu*)alloc((size_t)N * 128 * 2);
    bfu* X1lo = (bfu*)alloc((size_t)N * 128 * 2);
    bfu* X2hi = (bfu*)alloc((size_t)N * 256 * 2);
    bfu* X2lo = (bfu*)alloc((size_t)N * 256 * 2);
    bfu* X3hi = (bfu*)alloc((size_t)N * 512 * 2);
    bfu* X3lo = (bfu*)alloc((size_t)N * 512 * 2);
    bfu* tbhi = (bfu*)alloc((size_t)N * 64 * 2);
    bfu* tblo = (bfu*)alloc((size_t)N * 64 * 2);
    // transposed weight hi/lo planes
    bfu* w1t_hi[3]; bfu* w1t_lo[3]; bfu* w2t_hi[3]; bfu* w2t_lo[3];
    const int Ks[3] = {64, 128, 256};
    for (int l = 0; l < 3; l++) {
        w1t_hi[l] = (bfu*)alloc((size_t)64 * Ks[l] * 2);
        w1t_lo[l] = (bfu*)alloc((size_t)64 * Ks[l] * 2);
        w2t_hi[l] = (bfu*)alloc((size_t)Ks[l] * 64 * 2);
        w2t_lo[l] = (bfu*)alloc((size_t)Ks[l] * 64 * 2);
    }
    float* pooled = (float*)alloc((size_t)NC * 512 * 4);
    float* sumsq  = (float*)alloc(512 * 4);
    int*   deg    = (int*)alloc((size_t)(N + 1) * 4);
    int*   rowptr = (int*)alloc((size_t)(N + 1) * 4);
    int*   cursor = (int*)alloc((size_t)(N + 1) * 4);
    int*   colidx = (int*)alloc((size_t)E * 4);
    int*   cdeg   = (int*)alloc((size_t)(NC + 1) * 4);
    int*   cptr   = (int*)alloc((size_t)(NC + 1) * 4);
    int*   ccur   = (int*)alloc((size_t)(NC + 1) * 4);
    int*   cidx   = (int*)alloc((size_t)N * 4);
    int*   scn0   = (int*)alloc((size_t)N * 4);
    int*   scn1   = (int*)alloc((size_t)NC * 4);
    int*   bsum0  = (int*)alloc(256 * 4);
    int*   bsum1  = (int*)alloc(256 * 4);

    const int* src = ei;
    const int* dst = ei + E;

    k_zero3<<<(N + 255) / 256, 256, 0, stream>>>(deg, N, cdeg, NC, sumsq);

    // fused histograms
    k_hist2<<<(E + 255) / 256, 256, 0, stream>>>(dst, E, deg, cluster, N, cdeg);

    // hierarchical exclusive scan of both segments
    const int nb0 = (N + 255) / 256;
    const int nb1 = (NC + 255) / 256;
    k_scanA<<<dim3(nb0, 2), 256, 0, stream>>>(deg, N, cdeg, NC, scn0, scn1, bsum0, bsum1);
    k_scanB<<<1, 256, 0, stream>>>(bsum0, nb0, bsum1, nb1, rowptr, N, cptr, NC);
    k_scanC<<<dim3(nb0, 2), 256, 0, stream>>>(deg, N, cdeg, NC, scn0, scn1, bsum0, bsum1,
                                              rowptr, cursor, cptr, ccur);

    // fused scatters
    k_scatter2<<<(E + 255) / 256, 256, 0, stream>>>(dst, src, E, cursor, colidx,
                                                    cluster, N, ccur, cidx);

    // fused conversion: 6 weights (transposed hi/lo) + x0 (hi/lo)
    P6 pa;
    for (int l = 0; l < 3; l++) {
        pa.w[2 * l]     = w1_[l]; pa.hi[2 * l]     = w1t_hi[l]; pa.lo[2 * l]     = w1t_lo[l];
        pa.K[2 * l]     = Ks[l];  pa.Nw[2 * l]     = 64;
        pa.w[2 * l + 1] = w2_[l]; pa.hi[2 * l + 1] = w2t_hi[l]; pa.lo[2 * l + 1] = w2t_lo[l];
        pa.K[2 * l + 1] = 64;     pa.Nw[2 * l + 1] = Ks[l];
    }
    pa.x0 = x0; pa.xhi = X0hi; pa.xlo = X0lo; pa.xtotal = N * 64;
    k_prep_all<<<dim3((N * 64 / 4 + 255) / 256, 7), 256, 0, stream>>>(pa);

    const int Mt = (N + 127) / 128;
    const int aggBlocks = (N * 64 + 255) / 256;

    // layer 0: c=64
    k_gmfma<true><<<dim3(Mt, 1), 256, 0, stream>>>(X0hi, X0lo, w1t_hi[0], w1t_lo[0], b1_[0], tbhi, tblo, N, 64, 64, 64);
    k_gmfma<false><<<dim3(Mt, 1), 256, 0, stream>>>(tbhi, tblo, w2t_hi[0], w2t_lo[0], b2_[0], X1hi, X1lo, N, 64, 128, 64);
    k_agg<1><<<aggBlocks, 256, 0, stream>>>(X1hi, X1hi, rowptr, colidx, N, 128);

    // layer 1: c=128  (Alo for k>=64 is the aggr half: structurally zero)
    k_gmfma<true><<<dim3(Mt, 1), 256, 0, stream>>>(X1hi, X1lo, w1t_hi[1], w1t_lo[1], b1_[1], tbhi, tblo, N, 128, 64, 64);
    k_gmfma<false><<<dim3(Mt, 2), 256, 0, stream>>>(tbhi, tblo, w2t_hi[1], w2t_lo[1], b2_[1], X2hi, X2lo, N, 64, 256, 64);
    k_agg<2><<<aggBlocks, 256, 0, stream>>>(X2hi, X2hi, rowptr, colidx, N, 256);

    // layer 2: c=256  (Alo for k>=128 structurally zero)
    k_gmfma<true><<<dim3(Mt, 1), 256, 0, stream>>>(X2hi, X2lo, w1t_hi[2], w1t_lo[2], b1_[2], tbhi, tblo, N, 256, 64, 128);
    k_gmfma<false><<<dim3(Mt, 4), 256, 0, stream>>>(tbhi, tblo, w2t_hi[2], w2t_lo[2], b2_[2], X3hi, X3lo, N, 64, 512, 64);
    k_agg<4><<<aggBlocks, 256, 0, stream>>>(X3hi, X3hi, rowptr, colidx, N, 512);

    // cluster max-pool + column norm
    k_pool<<<NC, 256, 0, stream>>>(X3hi, X3lo, cptr, cidx, pooled);
    k_sumsq<<<64, 256, 0, stream>>>(pooled, sumsq, NC);
    k_scale<<<(out_size / 4 + 255) / 256, 256, 0, stream>>>(pooled, sumsq, out, out_size);
}

// Round 9
// 335.199 us; speedup vs baseline: 2.4886x; 1.0569x over previous
//
#include <hip/hip_runtime.h>
#include <math.h>

typedef unsigned short bfu;
typedef __attribute__((ext_vector_type(8))) short bf16x8;
typedef __attribute__((ext_vector_type(16))) float f32x16;

__device__ __forceinline__ float b2f(bfu u) {
    unsigned int x = ((unsigned int)u) << 16;
    return __uint_as_float(x);
}
__device__ __forceinline__ bfu f2bf(float f) {
    unsigned int u = __float_as_uint(f);
    unsigned int r = (u + 0x7FFFu + ((u >> 16) & 1u)) >> 16;
    return (bfu)r;
}

// ---------------------------------------------------------------------------
// fused init: zeros (y=0) + 6 weight transposes to hi/lo (y=1..6) + x0 cvt (y=7)
// ---------------------------------------------------------------------------
struct InitArgs {
    int* deg; int N; int* cdeg; int NC; float* sumsq;
    const float* w[6]; bfu* whi[6]; bfu* wlo[6]; int K[6]; int Nw[6];
    const float* x0; bfu* xhi; bfu* xlo; int xtotal;
};

__global__ __launch_bounds__(256) void k_init(InitArgs a) {
    const int j = blockIdx.y;
    const int g0 = blockIdx.x * 256 + threadIdx.x;
    const int gs = gridDim.x * 256;
    if (j == 0) {
        for (int i = g0; i < a.N; i += gs) a.deg[i] = 0;
        for (int i = g0; i < a.NC; i += gs) a.cdeg[i] = 0;
        for (int i = g0; i < 512; i += gs) a.sumsq[i] = 0.f;
    } else if (j <= 6) {
        const int jj = j - 1;
        const int K = a.K[jj], Nw = a.Nw[jj];
        const int total = K * Nw;
        const float* w = a.w[jj];
        bfu* dhi = a.whi[jj];
        bfu* dlo = a.wlo[jj];
        for (int idx = g0; idx < total; idx += gs) {
            int k = idx / Nw, n = idx % Nw;
            float v = w[idx];
            bfu hi = f2bf(v);
            bfu lo = f2bf(v - b2f(hi));
            dhi[n * K + k] = hi;
            dlo[n * K + k] = lo;
        }
    } else {
        for (int i = g0; i * 4 < a.xtotal; i += gs) {
            int base = i * 4;
            float4 v = *(const float4*)&a.x0[base];
            ushort4 h, l;
            h.x = f2bf(v.x); l.x = f2bf(v.x - b2f(h.x));
            h.y = f2bf(v.y); l.y = f2bf(v.y - b2f(h.y));
            h.z = f2bf(v.z); l.z = f2bf(v.z - b2f(h.z));
            h.w = f2bf(v.w); l.w = f2bf(v.w - b2f(h.w));
            *(ushort4*)&a.xhi[base] = h;
            *(ushort4*)&a.xlo[base] = l;
        }
    }
}

// ---------------------------------------------------------------------------
// fused histograms: edge-dst -> deg[N], cluster -> cdeg[NC]
// ---------------------------------------------------------------------------
__global__ void k_hist2(const int* __restrict__ dst, int E, int* __restrict__ deg,
                        const int* __restrict__ cluster, int N, int* __restrict__ cdeg) {
    int i = blockIdx.x * blockDim.x + threadIdx.x;
    if (i < E) atomicAdd(&deg[dst[i]], 1);
    if (i < N) atomicAdd(&cdeg[cluster[i]], 1);
}

__global__ __launch_bounds__(256) void k_scanA(const int* __restrict__ deg, int N,
                                               const int* __restrict__ cdeg, int NC,
                                               int* __restrict__ scn0, int* __restrict__ scn1,
                                               int* __restrict__ bsum0, int* __restrict__ bsum1) {
    __shared__ int part[256];
    const int seg = blockIdx.y;
    const int n = seg ? NC : N;
    const int* d = seg ? cdeg : deg;
    int* scn = seg ? scn1 : scn0;
    int* bs  = seg ? bsum1 : bsum0;
    const int b = blockIdx.x;
    if (b * 256 >= n) return;
    const int t = threadIdx.x;
    const int i = b * 256 + t;
    int v = (i < n) ? d[i] : 0;
    part[t] = v;
    __syncthreads();
#pragma unroll
    for (int off = 1; off < 256; off <<= 1) {
        int cv = part[t];
        int u = (t >= off) ? part[t - off] : 0;
        __syncthreads();
        part[t] = cv + u;
        __syncthreads();
    }
    if (i < n) scn[i] = part[t];
    if (t == 255) bs[b] = part[255];
}

__global__ __launch_bounds__(256) void k_scanB(int* __restrict__ bsum0, int nb0,
                                               int* __restrict__ bsum1, int nb1,
                                               int* __restrict__ ptr0, int N,
                                               int* __restrict__ ptr1, int NC) {
    __shared__ int part[256];
    const int t = threadIdx.x;
    int v = (t < nb0) ? bsum0[t] : 0;
    part[t] = v;
    __syncthreads();
#pragma unroll
    for (int off = 1; off < 256; off <<= 1) {
        int cv = part[t];
        int u = (t >= off) ? part[t - off] : 0;
        __syncthreads();
        part[t] = cv + u;
        __syncthreads();
    }
    if (t < nb0) bsum0[t] = part[t] - v;
    if (t == 255) ptr0[N] = part[255];
    __syncthreads();
    v = (t < nb1) ? bsum1[t] : 0;
    part[t] = v;
    __syncthreads();
#pragma unroll
    for (int off = 1; off < 256; off <<= 1) {
        int cv = part[t];
        int u = (t >= off) ? part[t - off] : 0;
        __syncthreads();
        part[t] = cv + u;
        __syncthreads();
    }
    if (t < nb1) bsum1[t] = part[t] - v;
    if (t == 255) ptr1[NC] = part[255];
}

__global__ __launch_bounds__(256) void k_scanC(const int* __restrict__ deg, int N,
                                               const int* __restrict__ cdeg, int NC,
                                               const int* __restrict__ scn0, const int* __restrict__ scn1,
                                               const int* __restrict__ bsum0, const int* __restrict__ bsum1,
                                               int* __restrict__ ptr0, int* __restrict__ cur0,
                                               int* __restrict__ ptr1, int* __restrict__ cur1) {
    const int seg = blockIdx.y;
    const int n = seg ? NC : N;
    const int* d = seg ? cdeg : deg;
    const int* scn = seg ? scn1 : scn0;
    const int* bs  = seg ? bsum1 : bsum0;
    int* ptr = seg ? ptr1 : ptr0;
    int* cur = seg ? cur1 : cur0;
    const int b = blockIdx.x;
    if (b * 256 >= n) return;
    const int i = b * 256 + threadIdx.x;
    if (i < n) {
        int e = bs[b] + scn[i] - d[i];
        ptr[i] = e;
        cur[i] = e;
    }
}

// ---------------------------------------------------------------------------
// fused scatters: edges -> colidx, nodes -> cidx
// ---------------------------------------------------------------------------
__global__ void k_scatter2(const int* __restrict__ dst, const int* __restrict__ src, int E,
                           int* __restrict__ cur, int* __restrict__ colidx,
                           const int* __restrict__ cluster, int N,
                           int* __restrict__ ccur, int* __restrict__ cidx) {
    int i = blockIdx.x * blockDim.x + threadIdx.x;
    if (i < E) {
        int d = dst[i];
        int pos = atomicAdd(&cur[d], 1);
        colidx[pos] = src[i];
    }
    if (i < N) {
        int c = cluster[i];
        int pos = atomicAdd(&ccur[c], 1);
        cidx[pos] = i;
    }
}

// ---------------------------------------------------------------------------
// MFMA GEMM (split-bf16, 3-product): O = act(A @ B + bias)
//   A: hi/lo bf16 planes [M][K] row-major; for k0 >= Kzero lo is structurally 0.
//   B: hi/lo planes [Nglobal][K] pre-transposed; tile n0 = blockIdx.y*64.
//   O: hi plane always; lo plane only if WLO.
//   128x64 tile, 4 waves, LDS XOR-swizzle byte ^= (row&7)<<4.
// ---------------------------------------------------------------------------
__device__ __forceinline__ int swz(int row, int kb) {
    return (row * 128 + (kb ^ ((row & 7) << 4))) >> 1;  // ushort index
}

template <bool RELU, bool WLO>
__global__ __launch_bounds__(256) void k_gmfma(const bfu* __restrict__ Ahi, const bfu* __restrict__ Alo,
                                               const bfu* __restrict__ Bhi, const bfu* __restrict__ Blo,
                                               const float* __restrict__ bias,
                                               bfu* __restrict__ Ohi, bfu* __restrict__ Olo,
                                               int M, int K, int OS, int Kzero) {
    __shared__ __align__(16) bfu As[2][128 * 64];
    __shared__ __align__(16) bfu Bs[2][64 * 64];
    const int tid = threadIdx.x;
    const int wave = tid >> 6, lane = tid & 63;
    const int m0 = blockIdx.x * 128;
    const int n0 = blockIdx.y * 64;
    const int l31 = lane & 31;
    const int khalfb = (lane >> 5) * 16;

    f32x16 acc0, acc1;
#pragma unroll
    for (int i = 0; i < 16; i++) { acc0[i] = 0.f; acc1[i] = 0.f; }

    for (int k0 = 0; k0 < K; k0 += 64) {
        const bool full3 = (k0 < Kzero);
#pragma unroll
        for (int i = 0; i < 4; i++) {
            int idx = i * 2048 + tid * 8;
            int row = idx >> 6;
            int ke = idx & 63;
            int gm = m0 + row; if (gm >= M) gm = M - 1;
            uint4 v = *(const uint4*)&Ahi[(size_t)gm * K + k0 + ke];
            *(uint4*)&As[0][swz(row, ke * 2)] = v;
        }
        if (full3) {
#pragma unroll
            for (int i = 0; i < 4; i++) {
                int idx = i * 2048 + tid * 8;
                int row = idx >> 6;
                int ke = idx & 63;
                int gm = m0 + row; if (gm >= M) gm = M - 1;
                uint4 v = *(const uint4*)&Alo[(size_t)gm * K + k0 + ke];
                *(uint4*)&As[1][swz(row, ke * 2)] = v;
            }
        }
#pragma unroll
        for (int p = 0; p < 2; p++) {
            const bfu* src = p ? Blo : Bhi;
#pragma unroll
            for (int i = 0; i < 2; i++) {
                int idx = i * 2048 + tid * 8;
                int row = idx >> 6;
                int ke = idx & 63;
                uint4 v = *(const uint4*)&src[(size_t)(n0 + row) * K + k0 + ke];
                *(uint4*)&Bs[p][swz(row, ke * 2)] = v;
            }
        }
        __syncthreads();
        const int arow = wave * 32 + l31;
#pragma unroll
        for (int s = 0; s < 4; s++) {
            int kb = s * 32 + khalfb;
            bf16x8 ah = *(const bf16x8*)&As[0][swz(arow, kb)];
            bf16x8 bh0 = *(const bf16x8*)&Bs[0][swz(l31, kb)];
            bf16x8 bl0 = *(const bf16x8*)&Bs[1][swz(l31, kb)];
            bf16x8 bh1 = *(const bf16x8*)&Bs[0][swz(32 + l31, kb)];
            bf16x8 bl1 = *(const bf16x8*)&Bs[1][swz(32 + l31, kb)];
            acc0 = __builtin_amdgcn_mfma_f32_32x32x16_bf16(ah, bh0, acc0, 0, 0, 0);
            acc0 = __builtin_amdgcn_mfma_f32_32x32x16_bf16(ah, bl0, acc0, 0, 0, 0);
            acc1 = __builtin_amdgcn_mfma_f32_32x32x16_bf16(ah, bh1, acc1, 0, 0, 0);
            acc1 = __builtin_amdgcn_mfma_f32_32x32x16_bf16(ah, bl1, acc1, 0, 0, 0);
            if (full3) {
                bf16x8 al = *(const bf16x8*)&As[1][swz(arow, kb)];
                acc0 = __builtin_amdgcn_mfma_f32_32x32x16_bf16(al, bh0, acc0, 0, 0, 0);
                acc1 = __builtin_amdgcn_mfma_f32_32x32x16_bf16(al, bh1, acc1, 0, 0, 0);
            }
        }
        __syncthreads();
    }

    float bc0 = bias[n0 + l31];
    float bc1 = bias[n0 + 32 + l31];
    const int rbase = m0 + wave * 32 + 4 * (lane >> 5);
#pragma unroll
    for (int r = 0; r < 16; r++) {
        int grow = rbase + (r & 3) + 8 * (r >> 2);
        if (grow < M) {
            float o0 = acc0[r] + bc0;
            float o1 = acc1[r] + bc1;
            if (RELU) { o0 = fmaxf(o0, 0.f); o1 = fmaxf(o1, 0.f); }
            bfu h0 = f2bf(o0), h1 = f2bf(o1);
            size_t base = (size_t)grow * OS + n0;
            Ohi[base + l31] = h0;
            Ohi[base + 32 + l31] = h1;
            if (WLO) {
                Olo[base + l31] = f2bf(o0 - b2f(h0));
                Olo[base + 32 + l31] = f2bf(o1 - b2f(h1));
            }
        }
    }
}

// ---------------------------------------------------------------------------
// Aggregation: per-node max over incoming edges (CSR).
// TWO nodes per wave, interleaved 4-deep each -> ~16 loads in flight.
// Gather h-part (cols [0,64R)) of hi plane; write bf16 max into cols [64R,128R).
// ---------------------------------------------------------------------------
template <int R>
__device__ __forceinline__ void gmax(const bfu* __restrict__ p, float* acc) {
    if (R == 4) {
        ushort4 v = *(const ushort4*)p;
        acc[0] = fmaxf(acc[0], b2f(v.x)); acc[1] = fmaxf(acc[1], b2f(v.y));
        acc[2] = fmaxf(acc[2], b2f(v.z)); acc[3] = fmaxf(acc[3], b2f(v.w));
    } else if (R == 2) {
        ushort2 v = *(const ushort2*)p;
        acc[0] = fmaxf(acc[0], b2f(v.x)); acc[1] = fmaxf(acc[1], b2f(v.y));
    } else {
        acc[0] = fmaxf(acc[0], b2f(*p));
    }
}

template <int R>
__global__ void k_agg(const bfu* __restrict__ hplane, bfu* __restrict__ whi,
                      const int* __restrict__ rowptr, const int* __restrict__ colidx,
                      int N, int stride) {
    const int w = (blockIdx.x * blockDim.x + threadIdx.x) >> 6;
    const int lane = threadIdx.x & 63;
    const int na = 2 * w, nb = na + 1;
    if (na >= N) return;
    const int ch = lane * R;
    const bool hasb = (nb < N);

    int bega = rowptr[na], enda = rowptr[na + 1];
    int begb = 0, endb = 0;
    if (hasb) { begb = rowptr[nb]; endb = rowptr[nb + 1]; }

    float acca[R], accb[R];
#pragma unroll
    for (int r = 0; r < R; r++) { acca[r] = -INFINITY; accb[r] = -INFINITY; }

    int ia = bega, ib = begb;
    while (ia + 4 <= enda && ib + 4 <= endb) {
        int offa[4], offb[4];
#pragma unroll
        for (int u = 0; u < 4; u++) {
            offa[u] = colidx[ia + u] * stride + ch;
            offb[u] = colidx[ib + u] * stride + ch;
        }
#pragma unroll
        for (int u = 0; u < 4; u++) {
            gmax<R>(hplane + offa[u], acca);
            gmax<R>(hplane + offb[u], accb);
        }
        ia += 4; ib += 4;
    }
    // drain a
    for (; ia + 4 <= enda; ia += 4) {
        int off[4];
#pragma unroll
        for (int u = 0; u < 4; u++) off[u] = colidx[ia + u] * stride + ch;
#pragma unroll
        for (int u = 0; u < 4; u++) gmax<R>(hplane + off[u], acca);
    }
    for (; ia < enda; ia++) gmax<R>(hplane + colidx[ia] * stride + ch, acca);
    // drain b
    for (; ib + 4 <= endb; ib += 4) {
        int off[4];
#pragma unroll
        for (int u = 0; u < 4; u++) off[u] = colidx[ib + u] * stride + ch;
#pragma unroll
        for (int u = 0; u < 4; u++) gmax<R>(hplane + off[u], accb);
    }
    for (; ib < endb; ib++) gmax<R>(hplane + colidx[ib] * stride + ch, accb);

    if (bega == enda) {
#pragma unroll
        for (int r = 0; r < R; r++) acca[r] = 0.f;
    }
    int obase = na * stride + 64 * R + ch;
#pragma unroll
    for (int r = 0; r < R; r++) whi[obase + r] = f2bf(acca[r]);

    if (hasb) {
        if (begb == endb) {
#pragma unroll
            for (int r = 0; r < R; r++) accb[r] = 0.f;
        }
        int obb = nb * stride + 64 * R + ch;
#pragma unroll
        for (int r = 0; r < R; r++) whi[obb + r] = f2bf(accb[r]);
    }
}

// ---------------------------------------------------------------------------
// Cluster max-pool from hi plane [M][512] only.
// ---------------------------------------------------------------------------
__global__ void k_pool(const bfu* __restrict__ xhi,
                       const int* __restrict__ cptr, const int* __restrict__ cidx,
                       float* __restrict__ pooled) {
    int cl = blockIdx.x;
    int tid = threadIdx.x;
    int beg = cptr[cl], end = cptr[cl + 1];
    float ax = -INFINITY, ay = -INFINITY;
    int i = beg;
    for (; i + 4 <= end; i += 4) {
        ushort2 h0 = *(const ushort2*)&xhi[cidx[i + 0] * 512 + tid * 2];
        ushort2 h1 = *(const ushort2*)&xhi[cidx[i + 1] * 512 + tid * 2];
        ushort2 h2 = *(const ushort2*)&xhi[cidx[i + 2] * 512 + tid * 2];
        ushort2 h3 = *(const ushort2*)&xhi[cidx[i + 3] * 512 + tid * 2];
        ax = fmaxf(ax, fmaxf(fmaxf(b2f(h0.x), b2f(h1.x)), fmaxf(b2f(h2.x), b2f(h3.x))));
        ay = fmaxf(ay, fmaxf(fmaxf(b2f(h0.y), b2f(h1.y)), fmaxf(b2f(h2.y), b2f(h3.y))));
    }
    for (; i < end; i++) {
        ushort2 h = *(const ushort2*)&xhi[cidx[i] * 512 + tid * 2];
        ax = fmaxf(ax, b2f(h.x)); ay = fmaxf(ay, b2f(h.y));
    }
    if (beg == end) { ax = 0.f; ay = 0.f; }
    float2 o; o.x = ax; o.y = ay;
    *(float2*)&pooled[(size_t)cl * 512 + tid * 2] = o;
}

// ---------------------------------------------------------------------------
// Column-wise sum of squares (axis 0), low-contention (64 blocks)
// ---------------------------------------------------------------------------
__global__ void k_sumsq(const float* __restrict__ pooled, float* __restrict__ sumsq, int NC) {
    int tid = threadIdx.x;
    float ax = 0.f, ay = 0.f;
    for (int r = blockIdx.x; r < NC; r += gridDim.x) {
        float2 v = *(const float2*)&pooled[(size_t)r * 512 + tid * 2];
        ax += v.x * v.x; ay += v.y * v.y;
    }
    atomicAdd(&sumsq[tid * 2 + 0], ax);
    atomicAdd(&sumsq[tid * 2 + 1], ay);
}

__global__ void k_scale(const float* __restrict__ pooled, const float* __restrict__ sumsq,
                        float* __restrict__ out, int total) {
    int i = blockIdx.x * blockDim.x + threadIdx.x;
    int base = i * 4;
    if (base < total) {
        float4 v = *(const float4*)&pooled[base];
        int col = base & 511;
        v.x /= (sqrtf(sumsq[col + 0]) + 1e-6f);
        v.y /= (sqrtf(sumsq[col + 1]) + 1e-6f);
        v.z /= (sqrtf(sumsq[col + 2]) + 1e-6f);
        v.w /= (sqrtf(sumsq[col + 3]) + 1e-6f);
        *(float4*)&out[base] = v;
    }
}

// ---------------------------------------------------------------------------
extern "C" void kernel_launch(void* const* d_in, const int* in_sizes, int n_in,
                              void* d_out, int out_size, void* d_ws, size_t ws_size,
                              hipStream_t stream) {
    const float* x0      = (const float*)d_in[0];
    const int*   ei      = (const int*)d_in[1];
    const int*   cluster = (const int*)d_in[2];
    const float* w1_[3] = {(const float*)d_in[3], (const float*)d_in[7],  (const float*)d_in[11]};
    const float* b1_[3] = {(const float*)d_in[4], (const float*)d_in[8],  (const float*)d_in[12]};
    const float* w2_[3] = {(const float*)d_in[5], (const float*)d_in[9],  (const float*)d_in[13]};
    const float* b2_[3] = {(const float*)d_in[6], (const float*)d_in[10], (const float*)d_in[14]};

    const int N  = in_sizes[2];       // 50000
    const int E  = in_sizes[1] / 2;   // 800000
    const int NC = 2500;
    float* out = (float*)d_out;

    char* p = (char*)d_ws;
    auto alloc = [&](size_t bytes) -> char* {
        char* r = p;
        p += (bytes + 255) & ~(size_t)255;
        return r;
    };
    bfu* X0hi = (bfu*)alloc((size_t)N * 64 * 2);
    bfu* X0lo = (bfu*)alloc((size_t)N * 64 * 2);
    bfu* X1hi = (bfu*)alloc((size_t)N * 128 * 2);
    bfu* X1lo = (bfu*)alloc((size_t)N * 128 * 2);
    bfu* X2hi = (bfu*)alloc((size_t)N * 256 * 2);
    bfu* X2lo = (bfu*)alloc((size_t)N * 256 * 2);
    bfu* X3hi = (bfu*)alloc((size_t)N * 512 * 2);
    bfu* tbhi = (bfu*)alloc((size_t)N * 64 * 2);
    bfu* tblo = (bfu*)alloc((size_t)N * 64 * 2);
    bfu* w1t_hi[3]; bfu* w1t_lo[3]; bfu* w2t_hi[3]; bfu* w2t_lo[3];
    const int Ks[3] = {64, 128, 256};
    for (int l = 0; l < 3; l++) {
        w1t_hi[l] = (bfu*)alloc((size_t)64 * Ks[l] * 2);
        w1t_lo[l] = (bfu*)alloc((size_t)64 * Ks[l] * 2);
        w2t_hi[l] = (bfu*)alloc((size_t)Ks[l] * 64 * 2);
        w2t_lo[l] = (bfu*)alloc((size_t)Ks[l] * 64 * 2);
    }
    float* pooled = (float*)alloc((size_t)NC * 512 * 4);
    float* sumsq  = (float*)alloc(512 * 4);
    int*   deg    = (int*)alloc((size_t)(N + 1) * 4);
    int*   rowptr = (int*)alloc((size_t)(N + 1) * 4);
    int*   cursor = (int*)alloc((size_t)(N + 1) * 4);
    int*   colidx = (int*)alloc((size_t)E * 4);
    int*   cdeg   = (int*)alloc((size_t)(NC + 1) * 4);
    int*   cptr   = (int*)alloc((size_t)(NC + 1) * 4);
    int*   ccur   = (int*)alloc((size_t)(NC + 1) * 4);
    int*   cidx   = (int*)alloc((size_t)N * 4);
    int*   scn0   = (int*)alloc((size_t)N * 4);
    int*   scn1   = (int*)alloc((size_t)NC * 4);
    int*   bsum0  = (int*)alloc(256 * 4);
    int*   bsum1  = (int*)alloc(256 * 4);

    const int* src = ei;
    const int* dst = ei + E;

    // fused init: zeros + weight transposes + x0 conversion
    InitArgs ia;
    ia.deg = deg; ia.N = N; ia.cdeg = cdeg; ia.NC = NC; ia.sumsq = sumsq;
    for (int l = 0; l < 3; l++) {
        ia.w[2 * l]     = w1_[l]; ia.whi[2 * l]     = w1t_hi[l]; ia.wlo[2 * l]     = w1t_lo[l];
        ia.K[2 * l]     = Ks[l];  ia.Nw[2 * l]      = 64;
        ia.w[2 * l + 1] = w2_[l]; ia.whi[2 * l + 1] = w2t_hi[l]; ia.wlo[2 * l + 1] = w2t_lo[l];
        ia.K[2 * l + 1] = 64;     ia.Nw[2 * l + 1]  = Ks[l];
    }
    ia.x0 = x0; ia.xhi = X0hi; ia.xlo = X0lo; ia.xtotal = N * 64;
    k_init<<<dim3(128, 8), 256, 0, stream>>>(ia);

    // fused histograms
    k_hist2<<<(E + 255) / 256, 256, 0, stream>>>(dst, E, deg, cluster, N, cdeg);

    // hierarchical exclusive scan of both segments
    const int nb0 = (N + 255) / 256;
    const int nb1 = (NC + 255) / 256;
    k_scanA<<<dim3(nb0, 2), 256, 0, stream>>>(deg, N, cdeg, NC, scn0, scn1, bsum0, bsum1);
    k_scanB<<<1, 256, 0, stream>>>(bsum0, nb0, bsum1, nb1, rowptr, N, cptr, NC);
    k_scanC<<<dim3(nb0, 2), 256, 0, stream>>>(deg, N, cdeg, NC, scn0, scn1, bsum0, bsum1,
                                              rowptr, cursor, cptr, ccur);

    // fused scatters
    k_scatter2<<<(E + 255) / 256, 256, 0, stream>>>(dst, src, E, cursor, colidx,
                                                    cluster, N, ccur, cidx);

    const int Mt = (N + 127) / 128;
    const int aggBlocks = (((N + 1) / 2) * 64 + 255) / 256;

    // layer 0: c=64
    k_gmfma<true, true><<<dim3(Mt, 1), 256, 0, stream>>>(X0hi, X0lo, w1t_hi[0], w1t_lo[0], b1_[0], tbhi, tblo, N, 64, 64, 64);
    k_gmfma<false, true><<<dim3(Mt, 1), 256, 0, stream>>>(tbhi, tblo, w2t_hi[0], w2t_lo[0], b2_[0], X1hi, X1lo, N, 64, 128, 64);
    k_agg<1><<<aggBlocks, 256, 0, stream>>>(X1hi, X1hi, rowptr, colidx, N, 128);

    // layer 1: c=128  (Alo for k>=64 structurally zero)
    k_gmfma<true, true><<<dim3(Mt, 1), 256, 0, stream>>>(X1hi, X1lo, w1t_hi[1], w1t_lo[1], b1_[1], tbhi, tblo, N, 128, 64, 64);
    k_gmfma<false, true><<<dim3(Mt, 2), 256, 0, stream>>>(tbhi, tblo, w2t_hi[1], w2t_lo[1], b2_[1], X2hi, X2lo, N, 64, 256, 64);
    k_agg<2><<<aggBlocks, 256, 0, stream>>>(X2hi, X2hi, rowptr, colidx, N, 256);

    // layer 2: c=256  (Alo for k>=128 structurally zero; X3 lo plane dropped)
    k_gmfma<true, true><<<dim3(Mt, 1), 256, 0, stream>>>(X2hi, X2lo, w1t_hi[2], w1t_lo[2], b1_[2], tbhi, tblo, N, 256, 64, 128);
    k_gmfma<false, false><<<dim3(Mt, 4), 256, 0, stream>>>(tbhi, tblo, w2t_hi[2], w2t_lo[2], b2_[2], X3hi, nullptr, N, 64, 512, 64);
    k_agg<4><<<aggBlocks, 256, 0, stream>>>(X3hi, X3hi, rowptr, colidx, N, 512);

    // cluster max-pool + column norm
    k_pool<<<NC, 256, 0, stream>>>(X3hi, cptr, cidx, pooled);
    k_sumsq<<<64, 256, 0, stream>>>(pooled, sumsq, NC);
    k_scale<<<(out_size / 4 + 255) / 256, 256, 0, stream>>>(pooled, sumsq, out, out_size);
}

// Round 10
// 303.530 us; speedup vs baseline: 2.7482x; 1.1043x over previous
//
#include <hip/hip_runtime.h>
#include <math.h>

typedef unsigned short bfu;
typedef __attribute__((ext_vector_type(8))) short bf16x8;
typedef __attribute__((ext_vector_type(16))) float f32x16;

__device__ __forceinline__ float b2f(bfu u) {
    unsigned int x = ((unsigned int)u) << 16;
    return __uint_as_float(x);
}
__device__ __forceinline__ bfu f2bf(float f) {
    unsigned int u = __float_as_uint(f);
    unsigned int r = (u + 0x7FFFu + ((u >> 16) & 1u)) >> 16;
    return (bfu)r;
}

// ---------------------------------------------------------------------------
// fused init: zeros (y=0) + 6 weight transposes to hi/lo (y=1..6) + x0 cvt (y=7)
// ---------------------------------------------------------------------------
struct InitArgs {
    int* deg; int N; int* cdeg; int NC; float* sumsq;
    const float* w[6]; bfu* whi[6]; bfu* wlo[6]; int K[6]; int Nw[6];
    const float* x0; bfu* xhi; bfu* xlo; int xtotal;
};

__global__ __launch_bounds__(256) void k_init(InitArgs a) {
    const int j = blockIdx.y;
    const int g0 = blockIdx.x * 256 + threadIdx.x;
    const int gs = gridDim.x * 256;
    if (j == 0) {
        for (int i = g0; i < a.N; i += gs) a.deg[i] = 0;
        for (int i = g0; i < a.NC; i += gs) a.cdeg[i] = 0;
        for (int i = g0; i < 512; i += gs) a.sumsq[i] = 0.f;
    } else if (j <= 6) {
        const int jj = j - 1;
        const int K = a.K[jj], Nw = a.Nw[jj];
        const int total = K * Nw;
        const float* w = a.w[jj];
        bfu* dhi = a.whi[jj];
        bfu* dlo = a.wlo[jj];
        for (int idx = g0; idx < total; idx += gs) {
            int k = idx / Nw, n = idx % Nw;
            float v = w[idx];
            bfu hi = f2bf(v);
            bfu lo = f2bf(v - b2f(hi));
            dhi[n * K + k] = hi;
            dlo[n * K + k] = lo;
        }
    } else {
        for (int i = g0; i * 4 < a.xtotal; i += gs) {
            int base = i * 4;
            float4 v = *(const float4*)&a.x0[base];
            ushort4 h, l;
            h.x = f2bf(v.x); l.x = f2bf(v.x - b2f(h.x));
            h.y = f2bf(v.y); l.y = f2bf(v.y - b2f(h.y));
            h.z = f2bf(v.z); l.z = f2bf(v.z - b2f(h.z));
            h.w = f2bf(v.w); l.w = f2bf(v.w - b2f(h.w));
            *(ushort4*)&a.xhi[base] = h;
            *(ushort4*)&a.xlo[base] = l;
        }
    }
}

// ---------------------------------------------------------------------------
// fused histograms: edge-dst -> deg[N], cluster -> cdeg[NC]
// ---------------------------------------------------------------------------
__global__ void k_hist2(const int* __restrict__ dst, int E, int* __restrict__ deg,
                        const int* __restrict__ cluster, int N, int* __restrict__ cdeg) {
    int i = blockIdx.x * blockDim.x + threadIdx.x;
    if (i < E) atomicAdd(&deg[dst[i]], 1);
    if (i < N) atomicAdd(&cdeg[cluster[i]], 1);
}

// Phase A: per-block inclusive scan; store inclusive + raw block sums.
__global__ __launch_bounds__(256) void k_scanA(const int* __restrict__ deg, int N,
                                               const int* __restrict__ cdeg, int NC,
                                               int* __restrict__ scn0, int* __restrict__ scn1,
                                               int* __restrict__ bsum0, int* __restrict__ bsum1) {
    __shared__ int part[256];
    const int seg = blockIdx.y;
    const int n = seg ? NC : N;
    const int* d = seg ? cdeg : deg;
    int* scn = seg ? scn1 : scn0;
    int* bs  = seg ? bsum1 : bsum0;
    const int b = blockIdx.x;
    if (b * 256 >= n) return;
    const int t = threadIdx.x;
    const int i = b * 256 + t;
    int v = (i < n) ? d[i] : 0;
    part[t] = v;
    __syncthreads();
#pragma unroll
    for (int off = 1; off < 256; off <<= 1) {
        int cv = part[t];
        int u = (t >= off) ? part[t - off] : 0;
        __syncthreads();
        part[t] = cv + u;
        __syncthreads();
    }
    if (i < n) scn[i] = part[t];
    if (t == 255) bs[b] = part[255];
}

// Phase C: each block scans the (<=256) raw block sums in LDS, then
// ptr[i] = blockoff + incl[i] - d[i]; block 0 writes the total.
__global__ __launch_bounds__(256) void k_scanC(const int* __restrict__ deg, int N,
                                               const int* __restrict__ cdeg, int NC,
                                               const int* __restrict__ scn0, const int* __restrict__ scn1,
                                               const int* __restrict__ bsum0, int nb0,
                                               const int* __restrict__ bsum1, int nb1,
                                               int* __restrict__ ptr0, int* __restrict__ cur0,
                                               int* __restrict__ ptr1, int* __restrict__ cur1) {
    __shared__ int part[256];
    const int seg = blockIdx.y;
    const int n = seg ? NC : N;
    const int nb = seg ? nb1 : nb0;
    const int* d = seg ? cdeg : deg;
    const int* scn = seg ? scn1 : scn0;
    const int* bsum = seg ? bsum1 : bsum0;
    int* ptr = seg ? ptr1 : ptr0;
    int* cur = seg ? cur1 : cur0;
    const int b = blockIdx.x;
    if (b * 256 >= n) return;
    const int t = threadIdx.x;
    int v = (t < nb) ? bsum[t] : 0;
    part[t] = v;
    __syncthreads();
#pragma unroll
    for (int off = 1; off < 256; off <<= 1) {
        int cv = part[t];
        int u = (t >= off) ? part[t - off] : 0;
        __syncthreads();
        part[t] = cv + u;
        __syncthreads();
    }
    const int boff = (b == 0) ? 0 : part[b - 1];
    const int i = b * 256 + t;
    if (i < n) {
        int e = boff + scn[i] - d[i];
        ptr[i] = e;
        cur[i] = e;
    }
    if (b == 0 && t == 0) ptr[n] = part[nb - 1];
}

// ---------------------------------------------------------------------------
// fused scatters: edges -> colidx, nodes -> cidx
// ---------------------------------------------------------------------------
__global__ void k_scatter2(const int* __restrict__ dst, const int* __restrict__ src, int E,
                           int* __restrict__ cur, int* __restrict__ colidx,
                           const int* __restrict__ cluster, int N,
                           int* __restrict__ ccur, int* __restrict__ cidx) {
    int i = blockIdx.x * blockDim.x + threadIdx.x;
    if (i < E) {
        int d = dst[i];
        int pos = atomicAdd(&cur[d], 1);
        colidx[pos] = src[i];
    }
    if (i < N) {
        int c = cluster[i];
        int pos = atomicAdd(&ccur[c], 1);
        cidx[pos] = i;
    }
}

// ---------------------------------------------------------------------------
// Fused layer: T = relu(X@W1 + b1); O[:, 0:Nw2] = T@W2 + b2 (hi/lo bf16 planes)
//   X: hi/lo [M][K]; for k0 >= Kzero the lo plane is structurally zero.
//   W1: hi/lo [64][K] transposed; W2: hi/lo [Nw2][64] transposed.
//   O: hi plane always (row stride OS); lo plane only if WLO.
//   128-row tile, 4 waves; T kept in LDS between phases (same bf16 split as
//   the previous HBM round-trip -> bit-identical numerics).
//   LDS XOR-swizzle: byte ^= (row&7)<<4 (rows are 128B).
// ---------------------------------------------------------------------------
__device__ __forceinline__ int swz(int row, int kb) {
    return (row * 128 + (kb ^ ((row & 7) << 4))) >> 1;  // ushort index
}

template <bool WLO>
__global__ __launch_bounds__(256) void k_layer(const bfu* __restrict__ Ahi, const bfu* __restrict__ Alo,
                                               const bfu* __restrict__ W1hi, const bfu* __restrict__ W1lo,
                                               const float* __restrict__ b1,
                                               const bfu* __restrict__ W2hi, const bfu* __restrict__ W2lo,
                                               const float* __restrict__ b2,
                                               bfu* __restrict__ Ohi, bfu* __restrict__ Olo,
                                               int M, int K, int Kzero, int Nw2, int OS) {
    __shared__ __align__(16) bfu As[2][128 * 64];  // X tile, then T tile
    __shared__ __align__(16) bfu Bs[2][64 * 64];
    const int tid = threadIdx.x;
    const int wave = tid >> 6, lane = tid & 63;
    const int m0 = blockIdx.x * 128;
    const int l31 = lane & 31;
    const int khalfb = (lane >> 5) * 16;
    const int arow = wave * 32 + l31;

    // ---------------- phase 1: T = relu(X @ W1 + b1) ----------------
    f32x16 acc0, acc1;
#pragma unroll
    for (int i = 0; i < 16; i++) { acc0[i] = 0.f; acc1[i] = 0.f; }

    for (int k0 = 0; k0 < K; k0 += 64) {
        const bool full3 = (k0 < Kzero);
#pragma unroll
        for (int i = 0; i < 4; i++) {
            int idx = i * 2048 + tid * 8;
            int row = idx >> 6;
            int ke = idx & 63;
            int gm = m0 + row; if (gm >= M) gm = M - 1;
            uint4 v = *(const uint4*)&Ahi[(size_t)gm * K + k0 + ke];
            *(uint4*)&As[0][swz(row, ke * 2)] = v;
        }
        if (full3) {
#pragma unroll
            for (int i = 0; i < 4; i++) {
                int idx = i * 2048 + tid * 8;
                int row = idx >> 6;
                int ke = idx & 63;
                int gm = m0 + row; if (gm >= M) gm = M - 1;
                uint4 v = *(const uint4*)&Alo[(size_t)gm * K + k0 + ke];
                *(uint4*)&As[1][swz(row, ke * 2)] = v;
            }
        }
#pragma unroll
        for (int p = 0; p < 2; p++) {
            const bfu* src = p ? W1lo : W1hi;
#pragma unroll
            for (int i = 0; i < 2; i++) {
                int idx = i * 2048 + tid * 8;
                int row = idx >> 6;
                int ke = idx & 63;
                uint4 v = *(const uint4*)&src[(size_t)row * K + k0 + ke];
                *(uint4*)&Bs[p][swz(row, ke * 2)] = v;
            }
        }
        __syncthreads();
#pragma unroll
        for (int s = 0; s < 4; s++) {
            int kb = s * 32 + khalfb;
            bf16x8 ah = *(const bf16x8*)&As[0][swz(arow, kb)];
            bf16x8 bh0 = *(const bf16x8*)&Bs[0][swz(l31, kb)];
            bf16x8 bl0 = *(const bf16x8*)&Bs[1][swz(l31, kb)];
            bf16x8 bh1 = *(const bf16x8*)&Bs[0][swz(32 + l31, kb)];
            bf16x8 bl1 = *(const bf16x8*)&Bs[1][swz(32 + l31, kb)];
            acc0 = __builtin_amdgcn_mfma_f32_32x32x16_bf16(ah, bh0, acc0, 0, 0, 0);
            acc0 = __builtin_amdgcn_mfma_f32_32x32x16_bf16(ah, bl0, acc0, 0, 0, 0);
            acc1 = __builtin_amdgcn_mfma_f32_32x32x16_bf16(ah, bh1, acc1, 0, 0, 0);
            acc1 = __builtin_amdgcn_mfma_f32_32x32x16_bf16(ah, bl1, acc1, 0, 0, 0);
            if (full3) {
                bf16x8 al = *(const bf16x8*)&As[1][swz(arow, kb)];
                acc0 = __builtin_amdgcn_mfma_f32_32x32x16_bf16(al, bh0, acc0, 0, 0, 0);
                acc1 = __builtin_amdgcn_mfma_f32_32x32x16_bf16(al, bh1, acc1, 0, 0, 0);
            }
        }
        __syncthreads();
    }

    // bias + relu; write T (bf16 hi/lo split) into As
    {
        float bc0 = b1[l31];
        float bc1 = b1[32 + l31];
        const int rbase = wave * 32 + 4 * (lane >> 5);
#pragma unroll
        for (int r = 0; r < 16; r++) {
            int row = rbase + (r & 3) + 8 * (r >> 2);
            float t0 = fmaxf(acc0[r] + bc0, 0.f);
            float t1 = fmaxf(acc1[r] + bc1, 0.f);
            bfu h0 = f2bf(t0), h1 = f2bf(t1);
            bfu l0 = f2bf(t0 - b2f(h0)), l1 = f2bf(t1 - b2f(h1));
            As[0][swz(row, l31 * 2)] = h0;
            As[0][swz(row, (32 + l31) * 2)] = h1;
            As[1][swz(row, l31 * 2)] = l0;
            As[1][swz(row, (32 + l31) * 2)] = l1;
        }
    }

    // ---------------- phase 2: O-tile = T @ W2-tile + b2 ----------------
    for (int n0 = 0; n0 < Nw2; n0 += 64) {
        __syncthreads();
#pragma unroll
        for (int p = 0; p < 2; p++) {
            const bfu* src = p ? W2lo : W2hi;
#pragma unroll
            for (int i = 0; i < 2; i++) {
                int idx = i * 2048 + tid * 8;
                int row = idx >> 6;
                int ke = idx & 63;
                uint4 v = *(const uint4*)&src[(size_t)(n0 + row) * 64 + ke];
                *(uint4*)&Bs[p][swz(row, ke * 2)] = v;
            }
        }
        __syncthreads();
#pragma unroll
        for (int i = 0; i < 16; i++) { acc0[i] = 0.f; acc1[i] = 0.f; }
#pragma unroll
        for (int s = 0; s < 4; s++) {
            int kb = s * 32 + khalfb;
            bf16x8 th = *(const bf16x8*)&As[0][swz(arow, kb)];
            bf16x8 tl = *(const bf16x8*)&As[1][swz(arow, kb)];
            bf16x8 wh0 = *(const bf16x8*)&Bs[0][swz(l31, kb)];
            bf16x8 wl0 = *(const bf16x8*)&Bs[1][swz(l31, kb)];
            bf16x8 wh1 = *(const bf16x8*)&Bs[0][swz(32 + l31, kb)];
            bf16x8 wl1 = *(const bf16x8*)&Bs[1][swz(32 + l31, kb)];
            acc0 = __builtin_amdgcn_mfma_f32_32x32x16_bf16(th, wh0, acc0, 0, 0, 0);
            acc0 = __builtin_amdgcn_mfma_f32_32x32x16_bf16(th, wl0, acc0, 0, 0, 0);
            acc0 = __builtin_amdgcn_mfma_f32_32x32x16_bf16(tl, wh0, acc0, 0, 0, 0);
            acc1 = __builtin_amdgcn_mfma_f32_32x32x16_bf16(th, wh1, acc1, 0, 0, 0);
            acc1 = __builtin_amdgcn_mfma_f32_32x32x16_bf16(th, wl1, acc1, 0, 0, 0);
            acc1 = __builtin_amdgcn_mfma_f32_32x32x16_bf16(tl, wh1, acc1, 0, 0, 0);
        }
        float bc0 = b2[n0 + l31];
        float bc1 = b2[n0 + 32 + l31];
        const int rbase = m0 + wave * 32 + 4 * (lane >> 5);
#pragma unroll
        for (int r = 0; r < 16; r++) {
            int grow = rbase + (r & 3) + 8 * (r >> 2);
            if (grow < M) {
                float o0 = acc0[r] + bc0;
                float o1 = acc1[r] + bc1;
                bfu h0 = f2bf(o0), h1 = f2bf(o1);
                size_t base = (size_t)grow * OS + n0;
                Ohi[base + l31] = h0;
                Ohi[base + 32 + l31] = h1;
                if (WLO) {
                    Olo[base + l31] = f2bf(o0 - b2f(h0));
                    Olo[base + 32 + l31] = f2bf(o1 - b2f(h1));
                }
            }
        }
    }
}

// ---------------------------------------------------------------------------
// Aggregation: per-node max over incoming edges (CSR), wave per node.
// 8-deep ILP, 32-bit addressing. Gather cols [0,64R) of hi plane; write bf16
// max into cols [64R,128R). (R8-proven form.)
// ---------------------------------------------------------------------------
template <int R>
__device__ __forceinline__ void gmax(const bfu* __restrict__ p, float* acc) {
    if (R == 4) {
        ushort4 v = *(const ushort4*)p;
        acc[0] = fmaxf(acc[0], b2f(v.x)); acc[1] = fmaxf(acc[1], b2f(v.y));
        acc[2] = fmaxf(acc[2], b2f(v.z)); acc[3] = fmaxf(acc[3], b2f(v.w));
    } else if (R == 2) {
        ushort2 v = *(const ushort2*)p;
        acc[0] = fmaxf(acc[0], b2f(v.x)); acc[1] = fmaxf(acc[1], b2f(v.y));
    } else {
        acc[0] = fmaxf(acc[0], b2f(*p));
    }
}

template <int R>
__global__ void k_agg(const bfu* __restrict__ hplane, bfu* __restrict__ whi,
                      const int* __restrict__ rowptr, const int* __restrict__ colidx,
                      int N, int stride) {
    const int wid = (blockIdx.x * blockDim.x + threadIdx.x) >> 6;
    const int lane = threadIdx.x & 63;
    if (wid >= N) return;
    const int beg = rowptr[wid], end = rowptr[wid + 1];
    const int ch = lane * R;

    float acc[R];
#pragma unroll
    for (int r = 0; r < R; r++) acc[r] = -INFINITY;

    int i = beg;
    for (; i + 8 <= end; i += 8) {
        int off[8];
#pragma unroll
        for (int u = 0; u < 8; u++) off[u] = colidx[i + u] * stride + ch;
#pragma unroll
        for (int u = 0; u < 8; u++) gmax<R>(hplane + off[u], acc);
    }
    for (; i + 2 <= end; i += 2) {
        int o0 = colidx[i] * stride + ch;
        int o1 = colidx[i + 1] * stride + ch;
        gmax<R>(hplane + o0, acc);
        gmax<R>(hplane + o1, acc);
    }
    if (i < end) gmax<R>(hplane + colidx[i] * stride + ch, acc);

    if (beg == end) {
#pragma unroll
        for (int r = 0; r < R; r++) acc[r] = 0.f;
    }
    int obase = wid * stride + 64 * R + ch;
#pragma unroll
    for (int r = 0; r < R; r++) whi[obase + r] = f2bf(acc[r]);
}

// ---------------------------------------------------------------------------
// Cluster max-pool from hi plane [M][512] only.
// ---------------------------------------------------------------------------
__global__ void k_pool(const bfu* __restrict__ xhi,
                       const int* __restrict__ cptr, const int* __restrict__ cidx,
                       float* __restrict__ pooled) {
    int cl = blockIdx.x;
    int tid = threadIdx.x;
    int beg = cptr[cl], end = cptr[cl + 1];
    float ax = -INFINITY, ay = -INFINITY;
    int i = beg;
    for (; i + 4 <= end; i += 4) {
        ushort2 h0 = *(const ushort2*)&xhi[cidx[i + 0] * 512 + tid * 2];
        ushort2 h1 = *(const ushort2*)&xhi[cidx[i + 1] * 512 + tid * 2];
        ushort2 h2 = *(const ushort2*)&xhi[cidx[i + 2] * 512 + tid * 2];
        ushort2 h3 = *(const ushort2*)&xhi[cidx[i + 3] * 512 + tid * 2];
        ax = fmaxf(ax, fmaxf(fmaxf(b2f(h0.x), b2f(h1.x)), fmaxf(b2f(h2.x), b2f(h3.x))));
        ay = fmaxf(ay, fmaxf(fmaxf(b2f(h0.y), b2f(h1.y)), fmaxf(b2f(h2.y), b2f(h3.y))));
    }
    for (; i < end; i++) {
        ushort2 h = *(const ushort2*)&xhi[cidx[i] * 512 + tid * 2];
        ax = fmaxf(ax, b2f(h.x)); ay = fmaxf(ay, b2f(h.y));
    }
    if (beg == end) { ax = 0.f; ay = 0.f; }
    float2 o; o.x = ax; o.y = ay;
    *(float2*)&pooled[(size_t)cl * 512 + tid * 2] = o;
}

// ---------------------------------------------------------------------------
// Column-wise sum of squares (axis 0), low-contention (64 blocks)
// ---------------------------------------------------------------------------
__global__ void k_sumsq(const float* __restrict__ pooled, float* __restrict__ sumsq, int NC) {
    int tid = threadIdx.x;
    float ax = 0.f, ay = 0.f;
    for (int r = blockIdx.x; r < NC; r += gridDim.x) {
        float2 v = *(const float2*)&pooled[(size_t)r * 512 + tid * 2];
        ax += v.x * v.x; ay += v.y * v.y;
    }
    atomicAdd(&sumsq[tid * 2 + 0], ax);
    atomicAdd(&sumsq[tid * 2 + 1], ay);
}

__global__ void k_scale(const float* __restrict__ pooled, const float* __restrict__ sumsq,
                        float* __restrict__ out, int total) {
    int i = blockIdx.x * blockDim.x + threadIdx.x;
    int base = i * 4;
    if (base < total) {
        float4 v = *(const float4*)&pooled[base];
        int col = base & 511;
        v.x /= (sqrtf(sumsq[col + 0]) + 1e-6f);
        v.y /= (sqrtf(sumsq[col + 1]) + 1e-6f);
        v.z /= (sqrtf(sumsq[col + 2]) + 1e-6f);
        v.w /= (sqrtf(sumsq[col + 3]) + 1e-6f);
        *(float4*)&out[base] = v;
    }
}

// ---------------------------------------------------------------------------
extern "C" void kernel_launch(void* const* d_in, const int* in_sizes, int n_in,
                              void* d_out, int out_size, void* d_ws, size_t ws_size,
                              hipStream_t stream) {
    const float* x0      = (const float*)d_in[0];
    const int*   ei      = (const int*)d_in[1];
    const int*   cluster = (const int*)d_in[2];
    const float* w1_[3] = {(const float*)d_in[3], (const float*)d_in[7],  (const float*)d_in[11]};
    const float* b1_[3] = {(const float*)d_in[4], (const float*)d_in[8],  (const float*)d_in[12]};
    const float* w2_[3] = {(const float*)d_in[5], (const float*)d_in[9],  (const float*)d_in[13]};
    const float* b2_[3] = {(const float*)d_in[6], (const float*)d_in[10], (const float*)d_in[14]};

    const int N  = in_sizes[2];       // 50000
    const int E  = in_sizes[1] / 2;   // 800000
    const int NC = 2500;
    float* out = (float*)d_out;

    char* p = (char*)d_ws;
    auto alloc = [&](size_t bytes) -> char* {
        char* r = p;
        p += (bytes + 255) & ~(size_t)255;
        return r;
    };
    bfu* X0hi = (bfu*)alloc((size_t)N * 64 * 2);
    bfu* X0lo = (bfu*)alloc((size_t)N * 64 * 2);
    bfu* X1hi = (bfu*)alloc((size_t)N * 128 * 2);
    bfu* X1lo = (bfu*)alloc((size_t)N * 128 * 2);
    bfu* X2hi = (bfu*)alloc((size_t)N * 256 * 2);
    bfu* X2lo = (bfu*)alloc((size_t)N * 256 * 2);
    bfu* X3hi = (bfu*)alloc((size_t)N * 512 * 2);
    bfu* w1t_hi[3]; bfu* w1t_lo[3]; bfu* w2t_hi[3]; bfu* w2t_lo[3];
    const int Ks[3] = {64, 128, 256};
    for (int l = 0; l < 3; l++) {
        w1t_hi[l] = (bfu*)alloc((size_t)64 * Ks[l] * 2);
        w1t_lo[l] = (bfu*)alloc((size_t)64 * Ks[l] * 2);
        w2t_hi[l] = (bfu*)alloc((size_t)Ks[l] * 64 * 2);
        w2t_lo[l] = (bfu*)alloc((size_t)Ks[l] * 64 * 2);
    }
    float* pooled = (float*)alloc((size_t)NC * 512 * 4);
    float* sumsq  = (float*)alloc(512 * 4);
    int*   deg    = (int*)alloc((size_t)(N + 1) * 4);
    int*   rowptr = (int*)alloc((size_t)(N + 1) * 4);
    int*   cursor = (int*)alloc((size_t)(N + 1) * 4);
    int*   colidx = (int*)alloc((size_t)E * 4);
    int*   cdeg   = (int*)alloc((size_t)(NC + 1) * 4);
    int*   cptr   = (int*)alloc((size_t)(NC + 1) * 4);
    int*   ccur   = (int*)alloc((size_t)(NC + 1) * 4);
    int*   cidx   = (int*)alloc((size_t)N * 4);
    int*   scn0   = (int*)alloc((size_t)N * 4);
    int*   scn1   = (int*)alloc((size_t)NC * 4);
    int*   bsum0  = (int*)alloc(256 * 4);
    int*   bsum1  = (int*)alloc(256 * 4);

    const int* src = ei;
    const int* dst = ei + E;

    // fused init: zeros + weight transposes + x0 conversion
    InitArgs ia;
    ia.deg = deg; ia.N = N; ia.cdeg = cdeg; ia.NC = NC; ia.sumsq = sumsq;
    for (int l = 0; l < 3; l++) {
        ia.w[2 * l]     = w1_[l]; ia.whi[2 * l]     = w1t_hi[l]; ia.wlo[2 * l]     = w1t_lo[l];
        ia.K[2 * l]     = Ks[l];  ia.Nw[2 * l]      = 64;
        ia.w[2 * l + 1] = w2_[l]; ia.whi[2 * l + 1] = w2t_hi[l]; ia.wlo[2 * l + 1] = w2t_lo[l];
        ia.K[2 * l + 1] = 64;     ia.Nw[2 * l + 1]  = Ks[l];
    }
    ia.x0 = x0; ia.xhi = X0hi; ia.xlo = X0lo; ia.xtotal = N * 64;
    k_init<<<dim3(128, 8), 256, 0, stream>>>(ia);

    // fused histograms
    k_hist2<<<(E + 255) / 256, 256, 0, stream>>>(dst, E, deg, cluster, N, cdeg);

    // hierarchical exclusive scan (2 phases; C scans block sums inline)
    const int nb0 = (N + 255) / 256;
    const int nb1 = (NC + 255) / 256;
    k_scanA<<<dim3(nb0, 2), 256, 0, stream>>>(deg, N, cdeg, NC, scn0, scn1, bsum0, bsum1);
    k_scanC<<<dim3(nb0, 2), 256, 0, stream>>>(deg, N, cdeg, NC, scn0, scn1, bsum0, nb0, bsum1, nb1,
                                              rowptr, cursor, cptr, ccur);

    // fused scatters
    k_scatter2<<<(E + 255) / 256, 256, 0, stream>>>(dst, src, E, cursor, colidx,
                                                    cluster, N, ccur, cidx);

    const int Mt = (N + 127) / 128;
    const int aggBlocks = (N * 64 + 255) / 256;

    // layer 0: c=64
    k_layer<true><<<Mt, 256, 0, stream>>>(X0hi, X0lo, w1t_hi[0], w1t_lo[0], b1_[0],
                                          w2t_hi[0], w2t_lo[0], b2_[0], X1hi, X1lo,
                                          N, 64, 64, 64, 128);
    k_agg<1><<<aggBlocks, 256, 0, stream>>>(X1hi, X1hi, rowptr, colidx, N, 128);

    // layer 1: c=128  (Alo for k>=64 structurally zero)
    k_layer<true><<<Mt, 256, 0, stream>>>(X1hi, X1lo, w1t_hi[1], w1t_lo[1], b1_[1],
                                          w2t_hi[1], w2t_lo[1], b2_[1], X2hi, X2lo,
                                          N, 128, 64, 128, 256);
    k_agg<2><<<aggBlocks, 256, 0, stream>>>(X2hi, X2hi, rowptr, colidx, N, 256);

    // layer 2: c=256  (Alo for k>=128 structurally zero; X3 lo plane dropped)
    k_layer<false><<<Mt, 256, 0, stream>>>(X2hi, X2lo, w1t_hi[2], w1t_lo[2], b1_[2],
                                           w2t_hi[2], w2t_lo[2], b2_[2], X3hi, nullptr,
                                           N, 256, 128, 256, 512);
    k_agg<4><<<aggBlocks, 256, 0, stream>>>(X3hi, X3hi, rowptr, colidx, N, 512);

    // cluster max-pool + column norm
    k_pool<<<NC, 256, 0, stream>>>(X3hi, cptr, cidx, pooled);
    k_sumsq<<<64, 256, 0, stream>>>(pooled, sumsq, NC);
    k_scale<<<(out_size / 4 + 255) / 256, 256, 0, stream>>>(pooled, sumsq, out, out_size);
}